// Round 7
// baseline (2719.596 us; speedup 1.0000x reference)
//
#include <hip/hip_runtime.h>
#include <hip/hip_bf16.h>
#include <math.h>

typedef __hip_bfloat16 bf16;

// Problem constants
constexpr int CB   = 32;    // batch
constexpr int CN   = 256;   // tokens
constexpr int CD   = 384;   // model dim (incl. time)
constexpr int CDS  = 383;   // space dim
constexpr int CH   = 6;     // heads
constexpr int CHC  = 64;    // head channels (incl. time)
constexpr int CHCS = 63;    // head space channels
constexpr int CL   = 12;    // layers
constexpr int CMH  = 1536;  // mlp hidden (incl. time)
constexpr int CMHS = 1535;
constexpr int CROWS = CB * CN;        // 8192
constexpr int CKP  = 784;             // patch vector length (14*14*4)
constexpr int CKPP = 832;             // padded patch stride (mult of 64)
constexpr int CQN  = CH * CHCS;       // 378
constexpr int CQN3 = 3 * CQN;         // 1134 (fused qkv cols)

static inline int cdiv(int a, int b){ return (a + b - 1) / b; }

// MFMA frag types
typedef short bf8_t __attribute__((ext_vector_type(8)));
typedef float f4_t  __attribute__((ext_vector_type(4)));

// fp32 -> bf16 (RNE) raw
__device__ __forceinline__ unsigned short f2bf(float f) {
    union { float f; unsigned u; } x; x.f = f;
    unsigned r = x.u + 0x7FFFu + ((x.u >> 16) & 1u);
    return (unsigned short)(r >> 16);
}
__device__ __forceinline__ float bf2f(unsigned short h) {
    union { unsigned u; float f; } x; x.u = ((unsigned)h) << 16;
    return x.f;
}

// Dual-dtype input load: isb=1 -> bf16, isb=0 -> fp32. Wave-uniform isb.
__device__ __forceinline__ float ldin(const void* p, size_t i, int isb) {
    if (isb) return __bfloat162float(((const bf16*)p)[i]);
    return ((const float*)p)[i];
}

// ---------------------------------------------------------------------------
// Dtype detector (inputs fp32 expected; bf16 fallback).
// ---------------------------------------------------------------------------
__global__ __launch_bounds__(256)
void detect_kernel(const void* __restrict__ x, int* __restrict__ flag) {
    __shared__ int red[256];
    const unsigned short* u = (const unsigned short*)x;
    int cnt = 0;
    for (int i = threadIdx.x; i < 4096; i += 256) {
        unsigned short v = u[i];
        int e = (v >> 7) & 0xFF;
        cnt += (v == 0 || (e >= 96 && e <= 142)) ? 1 : 0;
    }
    red[threadIdx.x] = cnt;
    __syncthreads();
    for (int off = 128; off > 0; off >>= 1) {
        if (threadIdx.x < off) red[threadIdx.x] += red[threadIdx.x + off];
        __syncthreads();
    }
    if (threadIdx.x == 0) flag[0] = (red[0] >= 3482) ? 1 : 0;
}

// ---------------------------------------------------------------------------
// Weight pack: W[K,N] (fp32 or bf16; layer-strided) -> Wt[Npad][Kpad] bf16,
// transposed + zero-padded. fuse=1: fused-QKV col mapping from Wq/Wk/Wv.
// ---------------------------------------------------------------------------
__global__ __launch_bounds__(256)
void pack_wt_kernel(const void* __restrict__ Wa, const void* __restrict__ Wb,
                    const void* __restrict__ Wc, size_t srcBase, size_t srcStrideL,
                    int N, int K, int Kpad, unsigned short* __restrict__ dst,
                    size_t dstStrideL, int fuse, const int* __restrict__ flg) {
    int isb = flg[0];
    int n0 = blockIdx.x * 64, k0 = blockIdx.y * 64;
    size_t so = srcBase + srcStrideL * blockIdx.z;
    unsigned short* dl = dst + dstStrideL * blockIdx.z;
    __shared__ unsigned short t[64][65];
    int tid = threadIdx.x;
    #pragma unroll
    for (int it = 0; it < 16; ++it) {
        int flat = it * 256 + tid;
        int kk = flat >> 6, nn = flat & 63;
        int n = n0 + nn, k = k0 + kk;
        float v = 0.0f;
        if (n < N && k < K) {
            if (fuse) {
                int wh = n / 378, rem = n - wh * 378;
                int h = rem / 63, e = rem - h * 63;
                const void* s = (wh == 0) ? Wa : (wh == 1 ? Wb : Wc);
                v = ldin(s, so + ((size_t)h * 384 + k) * 63 + e, isb);
            } else {
                v = ldin(Wa, so + (size_t)k * N + n, isb);
            }
        }
        t[kk][nn] = f2bf(v);
    }
    __syncthreads();
    #pragma unroll
    for (int it = 0; it < 16; ++it) {
        int flat = it * 256 + tid;
        int nn = flat >> 6, kk = flat & 63;
        dl[(size_t)(n0 + nn) * Kpad + (k0 + kk)] = t[kk][nn];
    }
}

// Bias pack -> fp32 [L][Npad], zero-padded. fuse=1: fused qkv bias.
__global__ __launch_bounds__(256)
void pack_bias_kernel(const void* __restrict__ b0, const void* __restrict__ b1v,
                      const void* __restrict__ b2v, int N, int Npad, int fuse,
                      float* __restrict__ dst, const int* __restrict__ flg) {
    int isb = flg[0];
    int l = blockIdx.y;
    int n = blockIdx.x * 256 + threadIdx.x;
    if (n >= Npad) return;
    float v = 0.0f;
    if (n < N) {
        if (fuse) {
            int wh = n / 378, rem = n - wh * 378;
            const void* s = (wh == 0) ? b0 : (wh == 1 ? b1v : b2v);
            v = ldin(s, (size_t)l * 378 + rem, isb);
        } else {
            v = ldin(b0, (size_t)l * N + n, isb);
        }
    }
    dst[(size_t)l * Npad + n] = v;
}

// ---------------------------------------------------------------------------
// Patchify: x[B,3,224,224] -> patches[8192, CKPP] bf16 (stride-padded)
// ---------------------------------------------------------------------------
__global__ __launch_bounds__(256)
void patchify_kernel(const void* __restrict__ x, unsigned short* __restrict__ patches,
                     const int* __restrict__ flg) {
    int isb = flg[0];
    int idx = blockIdx.x * 256 + threadIdx.x;
    if (idx >= CB * 224 * 224) return;
    int col = idx % 224;
    int t   = idx / 224;
    int row = t % 224;
    int b   = t / 224;
    size_t base = ((size_t)b * 3) * 224 * 224 + (size_t)row * 224 + col;
    float r  = ldin(x, base, isb);
    float g  = ldin(x, base + 224 * 224, isb);
    float bl = ldin(x, base + 2 * 224 * 224, isb);
    float tt = sqrtf(1.0f + r * r + g * g + bl * bl);
    int gi = row / 14, pi = row % 14, gj = col / 14, pj = col % 14;
    int p = gi * 16 + gj;
    unsigned short* dp = patches + ((size_t)(b * CN + p)) * CKPP + (pi * 14 + pj) * 4;
    ushort4 w = make_ushort4(f2bf(tt), f2bf(r), f2bf(g), f2bf(bl));
    *(ushort4*)dp = w;
}

// zero the pad region [784, 832) of each patch row (bf16)
__global__ __launch_bounds__(256)
void padzero_kernel(unsigned short* __restrict__ patches) {
    int idx = blockIdx.x * 256 + threadIdx.x;
    if (idx >= CROWS * (CKPP - CKP)) return;
    int row = idx / (CKPP - CKP), off = idx % (CKPP - CKP);
    patches[(size_t)row * CKPP + CKP + off] = 0;
}

// ---------------------------------------------------------------------------
// MFMA GEMM v5: C[M,N] = A[M,lda] @ Bt[Npad,ldb]^T + bias.
// Software-pipelined 2-phase; XOR-swizzled LDS; MFMA order fixed.
// ---------------------------------------------------------------------------
template<int BM, int BN>
__global__ __launch_bounds__(256)
void gemm_bt_kernel(const unsigned short* __restrict__ A, int lda,
                    const unsigned short* __restrict__ Bt, int ldb,
                    const float* __restrict__ bias,
                    float* __restrict__ C, int N, int K) {
    constexpr int BK  = 64;
    constexpr int ACH = BM / 32;   // 16B staging chunks per thread (A)
    constexpr int BCH = BN / 32;
    constexpr int MFR = BM / 32;   // 16x16 m-frags per wave
    constexpr int NFR = BN / 32;
    __shared__ __align__(16) unsigned short As[BM * BK];
    __shared__ __align__(16) unsigned short Bs[BN * BK];
    const int tid = threadIdx.x;
    const int wave = tid >> 6, lane = tid & 63;
    const int wm = wave & 1, wn = wave >> 1;
    const int bm = blockIdx.y * BM, bn = blockIdx.x * BN;

    const unsigned short* aSrc[ACH]; unsigned short* aDst[ACH];
    #pragma unroll
    for (int it = 0; it < ACH; ++it) {
        int i = it * 256 + tid;
        int row = i >> 3, up = i & 7;
        aSrc[it] = A + (size_t)(bm + row) * lda + up * 8;
        aDst[it] = &As[row * BK + ((up ^ (row & 7)) * 8)];
    }
    const unsigned short* bSrc[BCH]; unsigned short* bDst[BCH];
    #pragma unroll
    for (int it = 0; it < BCH; ++it) {
        int i = it * 256 + tid;
        int row = i >> 3, up = i & 7;
        bSrc[it] = Bt + (size_t)(bn + row) * ldb + up * 8;
        bDst[it] = &Bs[row * BK + ((up ^ (row & 7)) * 8)];
    }

    f4_t acc[MFR][NFR] = {};
    bf8_t av[ACH], bv[BCH];
    #pragma unroll
    for (int it = 0; it < ACH; ++it) av[it] = *(const bf8_t*)(aSrc[it]);
    #pragma unroll
    for (int it = 0; it < BCH; ++it) bv[it] = *(const bf8_t*)(bSrc[it]);

    for (int k0 = 0; k0 < K; k0 += BK) {
        __syncthreads();   // previous tile's compute done -> LDS writable
        #pragma unroll
        for (int it = 0; it < ACH; ++it) *(bf8_t*)aDst[it] = av[it];
        #pragma unroll
        for (int it = 0; it < BCH; ++it) *(bf8_t*)bDst[it] = bv[it];
        __syncthreads();   // tile visible
        if (k0 + BK < K) {  // prefetch next tile; latency hides under MFMAs
            #pragma unroll
            for (int it = 0; it < ACH; ++it) av[it] = *(const bf8_t*)(aSrc[it] + k0 + BK);
            #pragma unroll
            for (int it = 0; it < BCH; ++it) bv[it] = *(const bf8_t*)(bSrc[it] + k0 + BK);
        }
        #pragma unroll
        for (int c = 0; c < 2; ++c) {
            bf8_t af[MFR], bfg[NFR];
            #pragma unroll
            for (int mi = 0; mi < MFR; ++mi) {
                int r = wm * (BM / 2) + mi * 16 + (lane & 15);
                int u = (c * 4 + (lane >> 4)) ^ (r & 7);
                af[mi] = *(const bf8_t*)&As[r * BK + u * 8];
            }
            #pragma unroll
            for (int ni = 0; ni < NFR; ++ni) {
                int cc = wn * (BN / 2) + ni * 16 + (lane & 15);
                int u = (c * 4 + (lane >> 4)) ^ (cc & 7);
                bfg[ni] = *(const bf8_t*)&Bs[cc * BK + u * 8];
            }
            #pragma unroll
            for (int mi = 0; mi < MFR; ++mi)
                #pragma unroll
                for (int ni = 0; ni < NFR; ++ni)
                    acc[mi][ni] = __builtin_amdgcn_mfma_f32_16x16x32_bf16(
                        af[mi], bfg[ni], acc[mi][ni], 0, 0, 0);
        }
    }

    const int colq = lane & 15, rowq = (lane >> 4) * 4;
    #pragma unroll
    for (int ni = 0; ni < NFR; ++ni) {
        int col = bn + wn * (BN / 2) + ni * 16 + colq;
        if (col >= N) continue;
        float bbv = bias[col];
        #pragma unroll
        for (int mi = 0; mi < MFR; ++mi) {
            int row = bm + wm * (BM / 2) + mi * 16 + rowq;
            #pragma unroll
            for (int r = 0; r < 4; ++r)
                C[(size_t)(row + r) * N + col] = acc[mi][ni][r] + bbv;
        }
    }
}

// ---------------------------------------------------------------------------
// add_time rows (+optional GELU). src [M,NS] fp32; dst [M,NS+1] fp32 (obf=0)
// or bf16 (obf=1). GELU tanh via overflow-safe __expf formulation.
// ---------------------------------------------------------------------------
__global__ __launch_bounds__(256)
void add_time_rows_kernel(const float* __restrict__ src, void* __restrict__ dst,
                          int NS, int do_gelu, int obf) {
    int row = blockIdx.x;
    int tid = threadIdx.x;
    __shared__ float buf[1536];
    __shared__ float red[256];
    const float* sr = src + (size_t)row * NS;
    float ss = 0.0f;
    for (int j = tid; j < NS; j += 256) {
        float vv = sr[j];
        if (do_gelu) {
            float x3 = vv * vv * vv;
            float u = 0.7978845608028654f * (vv + 0.044715f * x3);
            float e = __expf(-2.0f * fabsf(u));
            float th = copysignf((1.0f - e) / (1.0f + e), u);
            vv = 0.5f * vv * (1.0f + th);
        }
        buf[j] = vv;
        ss += vv * vv;
    }
    red[tid] = ss;
    __syncthreads();
    for (int off = 128; off > 0; off >>= 1) {
        if (tid < off) red[tid] += red[tid + off];
        __syncthreads();
    }
    float t = sqrtf(1.0f + red[0]);
    if (obf) {
        unsigned short* dr = (unsigned short*)dst + (size_t)row * (NS + 1);
        if (tid == 0) dr[0] = f2bf(t);
        for (int j = tid; j < NS; j += 256) dr[1 + j] = f2bf(buf[j]);
    } else {
        float* dr = (float*)dst + (size_t)row * (NS + 1);
        if (tid == 0) dr[0] = t;
        for (int j = tid; j < NS; j += 256) dr[1 + j] = buf[j];
    }
}

// ---------------------------------------------------------------------------
// Fused: out = lnormalize(base + scale * add_time(src)); src [M,383].
// (kept for the final layer where no LN follows)
// ---------------------------------------------------------------------------
__global__ __launch_bounds__(256)
void addtime_lresnet_kernel(const float* __restrict__ src,
                            const float* __restrict__ base, float scale,
                            float* __restrict__ out) {
    int row = blockIdx.x;
    int tid = threadIdx.x;
    const float* sr = src + (size_t)row * CDS;
    const float* br = base + (size_t)row * CD;
    __shared__ float red[256];
    float s0 = (tid > 0) ? sr[tid - 1] : 0.0f;
    float s1 = (tid < 128) ? sr[tid + 255] : 0.0f;
    red[tid] = s0 * s0 + s1 * s1;
    __syncthreads();
    for (int off = 128; off > 0; off >>= 1) {
        if (tid < off) red[tid] += red[tid + off];
        __syncthreads();
    }
    float t = sqrtf(1.0f + red[0]);
    __syncthreads();
    float y0 = (tid == 0) ? t : s0;
    float z0 = br[tid] + scale * y0;
    float z1 = (tid < 128) ? br[tid + 256] + scale * s1 : 0.0f;
    float c = (tid == 0) ? z0 * z0 : -z0 * z0;
    c -= z1 * z1;
    red[tid] = c;
    __syncthreads();
    for (int off = 128; off > 0; off >>= 1) {
        if (tid < off) red[tid] += red[tid + off];
        __syncthreads();
    }
    float rd = 1.0f / sqrtf(fmaxf(red[0], 1e-8f));
    float* orow = out + (size_t)row * CD;
    orow[tid] = z0 * rd;
    if (tid < 128) orow[256 + tid] = z1 * rd;
}

// ---------------------------------------------------------------------------
// Fused: h = lnormalize(base + scale*add_time(src));  hout <- h;
// then LorentzLayerNorm(h) -> lnout (fp32) + lnout_bf (bf16).
// ---------------------------------------------------------------------------
__global__ __launch_bounds__(256)
void addtime_lresnet_ln_kernel(const float* __restrict__ src,
                               const float* __restrict__ base, float scale,
                               const void* __restrict__ g, size_t goff,
                               const void* __restrict__ b, size_t boff,
                               float* __restrict__ hout,
                               float* __restrict__ lnout,
                               unsigned short* __restrict__ lnout_bf,
                               const int* __restrict__ flg) {
    int isb = flg[0];
    int row = blockIdx.x;
    int tid = threadIdx.x;
    const float* sr = src + (size_t)row * CDS;
    const float* br = base + (size_t)row * CD;
    __shared__ float red[256];
    __shared__ float red2[256];
    // --- add_time(src) ---
    float s0 = (tid > 0) ? sr[tid - 1] : 0.0f;
    float s1 = (tid < 128) ? sr[tid + 255] : 0.0f;
    red[tid] = s0 * s0 + s1 * s1;
    __syncthreads();
    for (int off = 128; off > 0; off >>= 1) {
        if (tid < off) red[tid] += red[tid + off];
        __syncthreads();
    }
    float t = sqrtf(1.0f + red[0]);
    __syncthreads();
    // --- lresnet ---
    float y0 = (tid == 0) ? t : s0;
    float z0 = br[tid] + scale * y0;
    float z1 = (tid < 128) ? br[256 + tid] + scale * s1 : 0.0f;
    float c = (tid == 0) ? z0 * z0 : -z0 * z0;
    c -= z1 * z1;
    red[tid] = c;
    __syncthreads();
    for (int off = 128; off > 0; off >>= 1) {
        if (tid < off) red[tid] += red[tid + off];
        __syncthreads();
    }
    float rd = 1.0f / sqrtf(fmaxf(red[0], 1e-8f));
    float h0 = z0 * rd;
    float h1 = z1 * rd;
    float* hr = hout + (size_t)row * CD;
    hr[tid] = h0;
    if (tid < 128) hr[256 + tid] = h1;
    __syncthreads();
    // --- layernorm over space ---
    float v0 = (tid > 0) ? h0 : 0.0f;
    float v1 = (tid < 128) ? h1 : 0.0f;
    red[tid]  = v0 + v1;
    red2[tid] = v0 * v0 + v1 * v1;
    __syncthreads();
    for (int off = 128; off > 0; off >>= 1) {
        if (tid < off) { red[tid] += red[tid + off]; red2[tid] += red2[tid + off]; }
        __syncthreads();
    }
    float mu  = red[0] * (1.0f / 383.0f);
    float var = red2[0] * (1.0f / 383.0f) - mu * mu;
    __syncthreads();
    float rstd = rsqrtf(var + 1e-5f);
    float w0 = 0.0f, w1 = 0.0f;
    if (tid > 0)
        w0 = (h0 - mu) * rstd * ldin(g, goff + tid - 1, isb) + ldin(b, boff + tid - 1, isb);
    if (tid < 128)
        w1 = (h1 - mu) * rstd * ldin(g, goff + 255 + tid, isb) + ldin(b, boff + 255 + tid, isb);
    red[tid] = w0 * w0 + w1 * w1;
    __syncthreads();
    for (int off = 128; off > 0; off >>= 1) {
        if (tid < off) red[tid] += red[tid + off];
        __syncthreads();
    }
    float t2 = sqrtf(1.0f + red[0]);
    float* orow = lnout + (size_t)row * CD;
    unsigned short* brow = lnout_bf + (size_t)row * CD;
    if (tid == 0) { orow[0] = t2; brow[0] = f2bf(t2); }
    else          { orow[tid] = w0; brow[tid] = f2bf(w0); }
    if (tid < 128) { orow[256 + tid] = w1; brow[256 + tid] = f2bf(w1); }
}

// ---------------------------------------------------------------------------
// Lorentz layernorm: x[M,384] -> out fp32 [M,384] + out_bf bf16 [M,384]
// ---------------------------------------------------------------------------
__global__ __launch_bounds__(256)
void llayernorm_kernel(const float* __restrict__ x, const void* __restrict__ g,
                       size_t goff, const void* __restrict__ b, size_t boff,
                       float* __restrict__ out, unsigned short* __restrict__ out_bf,
                       const int* __restrict__ flg) {
    int isb = flg[0];
    int row = blockIdx.x;
    int tid = threadIdx.x;
    const float* xr = x + (size_t)row * CD;
    __shared__ float red[256];
    __shared__ float red2[256];
    int j0 = tid, j1 = tid + 256;
    float v0 = xr[1 + j0];
    float v1 = (j1 < CDS) ? xr[1 + j1] : 0.0f;
    red[tid]  = v0 + v1;
    red2[tid] = v0 * v0 + v1 * v1;
    __syncthreads();
    for (int off = 128; off > 0; off >>= 1) {
        if (tid < off) { red[tid] += red[tid + off]; red2[tid] += red2[tid + off]; }
        __syncthreads();
    }
    float mu  = red[0] * (1.0f / 383.0f);
    float var = red2[0] * (1.0f / 383.0f) - mu * mu;
    __syncthreads();
    float rstd = rsqrtf(var + 1e-5f);
    float y0 = (v0 - mu) * rstd * ldin(g, goff + j0, isb) + ldin(b, boff + j0, isb);
    float y1 = 0.0f;
    if (j1 < CDS) y1 = (v1 - mu) * rstd * ldin(g, goff + j1, isb) + ldin(b, boff + j1, isb);
    red[tid] = y0 * y0 + y1 * y1;
    __syncthreads();
    for (int off = 128; off > 0; off >>= 1) {
        if (tid < off) red[tid] += red[tid + off];
        __syncthreads();
    }
    float t = sqrtf(1.0f + red[0]);
    float* orow = out + (size_t)row * CD;
    unsigned short* brow = out_bf + (size_t)row * CD;
    orow[1 + j0] = y0;  brow[1 + j0] = f2bf(y0);
    if (j1 < CDS) { orow[1 + j1] = y1; brow[1 + j1] = f2bf(y1); }
    if (tid == 0) { orow[0] = t; brow[0] = f2bf(t); }
}

// lresnet vs broadcast dual-dtype pe (scale = 1)
__global__ __launch_bounds__(256)
void lresnet_pe_kernel(const float* __restrict__ x, const void* __restrict__ pe,
                       float* __restrict__ out, const int* __restrict__ flg) {
    int isb = flg[0];
    int row = blockIdx.x;
    int tid = threadIdx.x;
    const float* xr = x + (size_t)row * CD;
    size_t pb = (size_t)(row & (CN - 1)) * CD;
    __shared__ float red[256];
    float z0 = xr[tid] + ldin(pe, pb + tid, isb);
    float z1 = 0.0f;
    float c = (tid == 0) ? z0 * z0 : -z0 * z0;
    if (tid < 128) { z1 = xr[256 + tid] + ldin(pe, pb + 256 + tid, isb); c -= z1 * z1; }
    red[tid] = c;
    __syncthreads();
    for (int off = 128; off > 0; off >>= 1) {
        if (tid < off) red[tid] += red[tid + off];
        __syncthreads();
    }
    float rd = 1.0f / sqrtf(fmaxf(red[0], 1e-8f));
    float* orow = out + (size_t)row * CD;
    orow[tid] = z0 * rd;
    if (tid < 128) orow[256 + tid] = z1 * rd;
}

// ---------------------------------------------------------------------------
// qkv finish v3: src[8192,1134] -> PRE-SPLIT bf16 planes with add_time:
//   qh/ql  [B*H,N,64]  (hi/lo split; time channel PRE-NEGATED -> attn copies)
//   kh     [B*H,N,64]  (hi only — QK compensation uses Q-lo only)
//   vh/vl  [B*H,N,64]  (hi/lo split)
// ---------------------------------------------------------------------------
__global__ __launch_bounds__(256)
void qkv_finish_kernel(const float* __restrict__ src,
                       unsigned short* __restrict__ qh, unsigned short* __restrict__ ql,
                       unsigned short* __restrict__ kh,
                       unsigned short* __restrict__ vh, unsigned short* __restrict__ vl) {
    int tid = threadIdx.x, wave = tid >> 6, lane = tid & 63;
    int row = blockIdx.x * 4 + wave;
    int b = row >> 8, n = row & 255;
    const float* srow = src + (size_t)row * CQN3;
    #pragma unroll
    for (int hs = 0; hs < 18; hs++) {
        int which = hs / 6, h = hs % 6;
        float y = (lane < CHCS) ? srow[hs * 63 + lane] : 0.0f;
        float ss = y * y;
        #pragma unroll
        for (int off = 32; off > 0; off >>= 1) ss += __shfl_xor(ss, off);
        float t = sqrtf(1.0f + ss);
        size_t base = (((size_t)(b * CH + h)) * CN + n) * CHC;
        if (which == 0) {
            if (lane < CHCS) {
                unsigned short hi = f2bf(y);
                qh[base + 1 + lane] = hi;
                ql[base + 1 + lane] = f2bf(y - bf2f(hi));
            }
            if (lane == 0) {
                float nt = -t;                 // Minkowski time sign pre-applied
                unsigned short hi = f2bf(nt);
                qh[base] = hi;
                ql[base] = f2bf(nt - bf2f(hi));
            }
        } else if (which == 1) {
            if (lane < CHCS) kh[base + 1 + lane] = f2bf(y);
            if (lane == 0)   kh[base] = f2bf(t);
        } else {
            if (lane < CHCS) {
                unsigned short hi = f2bf(y);
                vh[base + 1 + lane] = hi;
                vl[base + 1 + lane] = f2bf(y - bf2f(hi));
            }
            if (lane == 0) {
                unsigned short hi = f2bf(t);
                vh[base] = hi;
                vl[base] = f2bf(t - bf2f(hi));
            }
        }
    }
}

// ---------------------------------------------------------------------------
// Attention v8: v7 + minimal-barrier PV phase. Key insight: Pf slabs are
// WAVE-PRIVATE (writePf writes and pvpass reads only slabs wave*4+ks2), and
// same-wave LDS ops execute in order -> NO barrier needed between P-half
// transitions. Barriers only around shared Bv staging: 3 instead of 11.
// Product/accumulation order unchanged -> bit-identical output to v7.
// ---------------------------------------------------------------------------
__global__ __launch_bounds__(256)
void attn_kernel(const unsigned short* __restrict__ qh, const unsigned short* __restrict__ ql,
                 const unsigned short* __restrict__ kh,
                 const unsigned short* __restrict__ vh, const unsigned short* __restrict__ vl,
                 unsigned short* __restrict__ attcat) {
    __shared__ __align__(16) unsigned char smem[49152];
    unsigned short* Bk = (unsigned short*)smem;            // 32KB (QK phase)
    unsigned short* Pf = (unsigned short*)smem;            // 16KB (PV phase)
    unsigned short* Bv = (unsigned short*)(smem + 16384);  // 32KB (PV phase)
    int id = blockIdx.x;
    int nid = (id & 7) * 96 + (id >> 3);
    int bh = nid >> 2, qc = nid & 3;
    int h = bh % CH, b = bh / CH;
    int tid = threadIdx.x, wave = tid >> 6, lane = tid & 63;
    const unsigned short* qhb = qh + ((size_t)bh * CN + qc * 64) * CHC;
    const unsigned short* qlb = ql + ((size_t)bh * CN + qc * 64) * CHC;
    const unsigned short* khb = kh + (size_t)bh * CN * CHC;
    const unsigned short* vhb = vh + (size_t)bh * CN * CHC;
    const unsigned short* vlb = vl + (size_t)bh * CN * CHC;

    // ---- K staging: 16B u16 copies, swizzled b128 stores ----
    #pragma unroll
    for (int it = 0; it < 8; it++) {
        int flat = it * 256 + tid;
        int key = flat >> 3, c8 = flat & 7;
        bf8_t w = *(const bf8_t*)(khb + key * CHC + c8 * 8);
        int slab = (key >> 4) * 2 + (c8 >> 2);
        int lpw = ((key & 15) | ((c8 & 3) << 4)) ^ c8;
        *(bf8_t*)(Bk + (slab * 64 + lpw) * 8) = w;
    }

    // ---- Q fragments: direct u16 loads (hi + lo; time already negated) ----
    bf8_t ah[2], al[2];
    {
        int row = wave * 16 + (lane & 15);
        #pragma unroll
        for (int ks = 0; ks < 2; ks++) {
            int c4 = ks * 32 + (lane >> 4) * 8;
            ah[ks] = *(const bf8_t*)(qhb + row * CHC + c4);
            al[ks] = *(const bf8_t*)(qlb + row * CHC + c4);
        }
    }
    __syncthreads();

    // ---- QK^T (hi + lo compensation) ----
    int kx0 = lane ^ (lane >> 4);
    int kx1 = lane ^ (4 | (lane >> 4));
    f4_t s[16];
    #pragma unroll
    for (int nt = 0; nt < 16; nt++) s[nt] = (f4_t){0.0f, 0.0f, 0.0f, 0.0f};
    __builtin_amdgcn_s_setprio(1);
    #pragma unroll
    for (int nt = 0; nt < 16; nt++) {
        bf8_t b0 = *(const bf8_t*)(Bk + ((nt * 2 + 0) * 64 + kx0) * 8);
        bf8_t b1 = *(const bf8_t*)(Bk + ((nt * 2 + 1) * 64 + kx1) * 8);
        s[nt] = __builtin_amdgcn_mfma_f32_16x16x32_bf16(ah[0], b0, s[nt], 0, 0, 0);
        s[nt] = __builtin_amdgcn_mfma_f32_16x16x32_bf16(ah[1], b1, s[nt], 0, 0, 0);
        s[nt] = __builtin_amdgcn_mfma_f32_16x16x32_bf16(al[0], b0, s[nt], 0, 0, 0);
        s[nt] = __builtin_amdgcn_mfma_f32_16x16x32_bf16(al[1], b1, s[nt], 0, 0, 0);
    }
    __builtin_amdgcn_s_setprio(0);

    // ---- softmax (registers, wave-parallel) ----
    float mx[4] = {-1e30f, -1e30f, -1e30f, -1e30f};
    #pragma unroll
    for (int nt = 0; nt < 16; nt++)
        #pragma unroll
        for (int r = 0; r < 4; r++) mx[r] = fmaxf(mx[r], s[nt][r]);
    #pragma unroll
    for (int off = 1; off < 16; off <<= 1)
        #pragma unroll
        for (int r = 0; r < 4; r++) mx[r] = fmaxf(mx[r], __shfl_xor(mx[r], off));
    float sm[4] = {0.0f, 0.0f, 0.0f, 0.0f};
    #pragma unroll
    for (int nt = 0; nt < 16; nt++)
        #pragma unroll
        for (int r = 0; r < 4; r++) {
            float e = __expf(0.25f * (s[nt][r] - mx[r]));
            s[nt][r] = e; sm[r] += e;
        }
    #pragma unroll
    for (int off = 1; off < 16; off <<= 1)
        #pragma unroll
        for (int r = 0; r < 4; r++) sm[r] += __shfl_xor(sm[r], off);
    #pragma unroll
    for (int r = 0; r < 4; r++) sm[r] = 1.0f / sm[r];
    #pragma unroll
    for (int nt = 0; nt < 16; nt++)
        #pragma unroll
        for (int r = 0; r < 4; r++) s[nt][r] *= sm[r];

    __syncthreads();   // all QK reads of Bk complete (Pf/Bv alias it)

    int colq = lane & 15, quad = lane >> 4;
    // P half-write: slabs wave*4+ks2 (wave-private; same-wave LDS in-order)
    auto writePf = [&](int lo, int hh) {
        #pragma unroll
        for (int ntl = 0; ntl < 8; ntl++) {
            int nt = hh * 8 + ntl;
            int key = nt * 16 + colq;
            int ks2 = (key >> 5) & 3;
            #pragma unroll
            for (int r = 0; r < 4; r++) {
                int qrow = quad * 4 + r;
                int lp = (qrow & 15) | (((key >> 3) & 3) << 4);
                float p = s[nt][r];
                unsigned short hi = f2bf(p);
                unsigned short w = lo ? f2bf(p - bf2f(hi)) : hi;
                Pf[((wave * 4 + ks2) * 64 + lp) * 8 + (key & 7)] = w;
            }
        }
    };
    // V full-stage (256 keys): lane = dim, u16 copies, b128 LDS stores
    auto stageBv = [&](const unsigned short* plane) {
        #pragma unroll
        for (int i8 = 0; i8 < 8; i8++) {
            int oct = i8 * 4 + wave;
            bf8_t w;
            #pragma unroll
            for (int i = 0; i < 8; i++)
                w[i] = (short)plane[(size_t)(oct * 8 + i) * CHC + lane];
            int a16 = ((lane >> 4) * 8 + (oct >> 2)) * 64 + (oct & 3) * 16 + (lane & 15);
            *(bf8_t*)(Bv + a16 * 8) = w;
        }
    };
    f4_t o[4] = {};
    auto pvpass = [&](int hh) {
        __builtin_amdgcn_s_setprio(1);
        #pragma unroll
        for (int ks2 = 0; ks2 < 4; ks2++) {
            bf8_t pa = *(const bf8_t*)(Pf + ((wave * 4 + ks2) * 64 + lane) * 8);
            #pragma unroll
            for (int nt = 0; nt < 4; nt++) {
                bf8_t vv = *(const bf8_t*)(Bv + ((nt * 8 + hh * 4 + ks2) * 64 + lane) * 8);
                o[nt] = __builtin_amdgcn_mfma_f32_16x16x32_bf16(pa, vv, o[nt], 0, 0, 0);
            }
        }
        __builtin_amdgcn_s_setprio(0);
    };

    // Product order identical to v7: Ph*Vh(h0,h1), Pl*Vh(h0,h1), Ph*Vl(h0,h1)
    // Barriers ONLY around shared-Bv transitions (Pf is wave-private).
    writePf(0, 0); stageBv(vhb);
    __syncthreads();                 // Bv(hi) visible to all waves
    pvpass(0);
    writePf(0, 1); pvpass(1);
    writePf(1, 0); pvpass(0);
    writePf(1, 1); pvpass(1);
    __syncthreads();                 // all waves done reading Bv(hi)
    stageBv(vlb);
    __syncthreads();                 // Bv(lo) visible
    writePf(0, 0); pvpass(0);
    writePf(0, 1); pvpass(1);

    // ---- lnormalize + bf16 store ----
    {
        float nrm[4] = {0.0f, 0.0f, 0.0f, 0.0f};
        #pragma unroll
        for (int nt = 0; nt < 4; nt++) {
            float sgn = (nt == 0 && colq == 0) ? 1.0f : -1.0f;
            #pragma unroll
            for (int r = 0; r < 4; r++) nrm[r] += sgn * o[nt][r] * o[nt][r];
        }
        #pragma unroll
        for (int off = 1; off < 16; off <<= 1)
            #pragma unroll
            for (int r = 0; r < 4; r++) nrm[r] += __shfl_xor(nrm[r], off);
        #pragma unroll
        for (int r = 0; r < 4; r++) {
            float d = 1.0f / sqrtf(fmaxf(nrm[r], 1e-8f));
            int qg = qc * 64 + wave * 16 + quad * 4 + r;
            unsigned short* orow = attcat + ((size_t)b * CN + qg) * CD + h * CHC;
            #pragma unroll
            for (int nt = 0; nt < 4; nt++)
                orow[nt * 16 + colq] = f2bf(o[nt][r] * d);
        }
    }
}

// ---------------------------------------------------------------------------
// mean-pool v2: two-phase.
// ---------------------------------------------------------------------------
__global__ __launch_bounds__(256)
void meanpool_part_kernel(const float* __restrict__ hbuf, float* __restrict__ part) {
    int b = blockIdx.x, ch = blockIdx.y, tid = threadIdx.x;
    const float* hb = hbuf + ((size_t)b * CN + ch * 32) * CD;
    float s0 = 0.0f, s1 = 0.0f;
    for (int n = 0; n < 32; n++) {
        s0 += hb[(size_t)n * CD + tid];
        if (tid < 128) s1 += hb[(size_t)n * CD + 256 + tid];
    }
    float* pr = part + (size_t)(b * 8 + ch) * CD;
    pr[tid] = s0;
    if (tid < 128) pr[256 + tid] = s1;
}

__global__ __launch_bounds__(256)
void meanpool_fin_kernel(const float* __restrict__ part, float* __restrict__ emb) {
    int b = blockIdx.x, tid = threadIdx.x;
    float s0 = 0.0f, s1 = 0.0f;
    for (int c = 0; c < 8; c++) {
        const float* pr = part + (size_t)(b * 8 + c) * CD;
        s0 += pr[tid];
        if (tid < 128) s1 += pr[256 + tid];
    }
    s0 *= (1.0f / 256.0f);
    s1 *= (1.0f / 256.0f);
    __shared__ float red[256];
    float c2 = (tid == 0) ? s0 * s0 : -s0 * s0;
    if (tid < 128) c2 -= s1 * s1;
    red[tid] = c2;
    __syncthreads();
    for (int off = 128; off > 0; off >>= 1) {
        if (tid < off) red[tid] += red[tid + off];
        __syncthreads();
    }
    float rd = 1.0f / sqrtf(fmaxf(red[0], 1e-8f));
    emb[(size_t)b * CD + tid] = s0 * rd;
    if (tid < 128) emb[(size_t)b * CD + 256 + tid] = s1 * rd;
}

// ---------------------------------------------------------------------------
// MLR head precompute v2: wave-per-class, coalesced. grid (250), 256 thr.
// ---------------------------------------------------------------------------
__global__ __launch_bounds__(256)
void head_pre_kernel(const void* __restrict__ mlra, const void* __restrict__ mlrz,
                     float* __restrict__ wt, float* __restrict__ beta,
                     float* __restrict__ cha, const int* __restrict__ flg) {
    int isb = flg[0];
    int wave = threadIdx.x >> 6, lane = threadIdx.x & 63;
    int c = blockIdx.x * 4 + wave;
    float S = 0.0f;
    for (int j = lane; j < CDS; j += 64) {
        float zz = ldin(mlrz, (size_t)c * CDS + j, isb);
        S += zz * zz;
    }
    #pragma unroll
    for (int off = 32; off > 0; off >>= 1) S += __shfl_xor(S, off);
    if (lane == 0) {
        float a  = ldin(mlra, c, isb);
        float sh = sinhf(a), ch = coshf(a);
        float zn = sqrtf(S + 1e-8f);
        float w  = sh * zn;
        wt[c]  = w;
        cha[c] = ch;
        beta[c] = sqrtf(fmaxf(ch * ch * S - w * w, 1e-8f));
    }
}

// ---------------------------------------------------------------------------
// head logits v2: wave-per-class, lane-parallel over j, emb staged in LDS.
// ---------------------------------------------------------------------------
__global__ __launch_bounds__(256)
void head_logits_kernel(const float* __restrict__ emb, const void* __restrict__ mlrz,
                        const float* __restrict__ wt, const float* __restrict__ beta,
                        const float* __restrict__ cha, void* __restrict__ out,
                        const int* __restrict__ flg) {
    int isb = flg[0];
    int tid = threadIdx.x, wave = tid >> 6, lane = tid & 63;
    __shared__ float es[CB * CD];   // 48 KiB
    for (int i = tid; i < CB * CD; i += 256) es[i] = emb[i];
    __syncthreads();
    int c = blockIdx.x * 4 + wave;
    float zv[6];
    #pragma unroll
    for (int jj = 0; jj < 6; jj++) {
        int j = jj * 64 + lane;
        zv[jj] = (j < CDS) ? ldin(mlrz, (size_t)c * CDS + j, isb) : 0.0f;
    }
    float wtc = wt[c], chac = cha[c], bec = beta[c];
    for (int b = 0; b < CB; b++) {
        const float* eb = es + b * CD;
        float d = 0.0f;
        #pragma unroll
        for (int jj = 0; jj < 6; jj++) {
            int j = jj * 64 + lane;
            if (j < CDS) d += zv[jj] * eb[1 + j];
        }
        #pragma unroll
        for (int off = 32; off > 0; off >>= 1) d += __shfl_xor(d, off);
        if (lane == 0) {
            float alpha = -eb[0] * wtc + chac * d;
            float lg = bec * asinhf(alpha / bec);
            if (isb) ((bf16*)out)[(size_t)b * 1000 + c] = __float2bfloat16(lg);
            else     ((float*)out)[(size_t)b * 1000 + c] = lg;
        }
    }
}

// ---------------------------------------------------------------------------
// Orchestration. qkv planes (u16): qh|ql|kh|vh|vl each CROWS*CD elems,
// packed at big2 (2.5 FH floats total; xln_bf/attcat_bf at big2+3FH safe).
// ---------------------------------------------------------------------------
extern "C" void kernel_launch(void* const* d_in, const int* in_sizes, int n_in,
                              void* d_out, int out_size, void* d_ws, size_t ws_size,
                              hipStream_t stream) {
    const void* x      = d_in[0];
    const void* patchW = d_in[1];
    const void* patchB = d_in[2];
    const void* pe     = d_in[3];
    const void* ln1g   = d_in[4];
    const void* ln1b   = d_in[5];
    const void* ln2g   = d_in[6];
    const void* ln2b   = d_in[7];
    const void* Wq     = d_in[8];
    const void* bq     = d_in[9];
    const void* Wk     = d_in[10];
    const void* bk     = d_in[11];
    const void* Wv     = d_in[12];
    const void* bv     = d_in[13];
    const void* Wo     = d_in[14];
    const void* bo     = d_in[15];
    const void* W1     = d_in[16];
    const void* b1     = d_in[17];
    const void* W2     = d_in[18];
    const void* b2     = d_in[19];
    const void* mlra   = d_in[20];
    const void* mlrz   = d_in[21];

    float* ws = (float*)d_ws;
    const size_t FH = (size_t)CROWS * CD;
    float* hbuf   = ws;
    float* xln    = ws + FH;
    float* big1   = ws + 2 * FH;
    float* big2   = ws + 6 * FH;
    unsigned short* patches_bf = (unsigned short*)big1;
    unsigned short* hidden_bf  = (unsigned short*)big2;
    unsigned short* xln_bf     = (unsigned short*)(big2 + 3 * FH);
    unsigned short* attcat_bf  = (unsigned short*)(big2 + 3 * FH);
    // qkv bf16 planes (each FH u16 elems = FH/2 floats), total 2.5 FH floats
    unsigned short* qh  = (unsigned short*)big2;
    unsigned short* qlp = qh + FH;
    unsigned short* khp = qh + 2 * FH;
    unsigned short* vhp = qh + 3 * FH;
    unsigned short* vlp = qh + 4 * FH;
    float* emb    = ws + 10 * FH;
    float* wt     = emb + (size_t)CB * CD;
    float* beta   = wt + 1000;
    float* cha    = beta + 1000;
    int*   flag   = (int*)(cha + 1000);

    // packed biases (fp32)
    float* bias_patch = ws + 10 * FH + 16384;
    float* bias_qkv   = bias_patch + 384;
    float* bias_wo    = bias_qkv + (size_t)12 * 1152;
    float* bias_w1    = bias_wo  + (size_t)12 * 384;
    float* bias_w2    = bias_w1  + (size_t)12 * 1536;
    // packed weights (bf16)
    unsigned short* wt_patch = (unsigned short*)(bias_w2 + (size_t)12 * 384);
    unsigned short* wt_dyn   = wt_patch + (size_t)384 * 832;
    const size_t EQKV = (size_t)1152 * 384, EWO = (size_t)384 * 384,
                 EW1  = (size_t)1536 * 384, EW2 = (size_t)384 * 1536;
    unsigned short* wt_qkv = wt_dyn;
    unsigned short* wt_wo  = wt_qkv + 12 * EQKV;
    unsigned short* wt_w1  = wt_wo  + 12 * EWO;
    unsigned short* wt_w2  = wt_w1  + 12 * EW1;
    size_t need_full = (size_t)((char*)(wt_w2 + 12 * EW2) - (char*)d_ws);
    int full = (ws_size >= need_full) ? 1 : 0;
    // per-layer rotating buffers (aliased at wt_dyn)
    unsigned short* l_qkv = wt_dyn;
    unsigned short* l_wo  = l_qkv + EQKV;
    unsigned short* l_w1  = l_wo  + EWO;
    unsigned short* l_w2  = l_w1  + EW1;

    detect_kernel<<<1, 256, 0, stream>>>(x, flag);

    // pack biases
    pack_bias_kernel<<<dim3(2, 1),  256, 0, stream>>>(patchB, nullptr, nullptr, 383, 384, 0, bias_patch, flag);
    pack_bias_kernel<<<dim3(5, 12), 256, 0, stream>>>(bq, bk, bv, 1134, 1152, 1, bias_qkv, flag);
    pack_bias_kernel<<<dim3(2, 12), 256, 0, stream>>>(bo, nullptr, nullptr, 383, 384, 0, bias_wo, flag);
    pack_bias_kernel<<<dim3(6, 12), 256, 0, stream>>>(b1, nullptr, nullptr, 1535, 1536, 0, bias_w1, flag);
    pack_bias_kernel<<<dim3(2, 12), 256, 0, stream>>>(b2, nullptr, nullptr, 383, 384, 0, bias_w2, flag);

    // pack weights -> W^T bf16, zero-padded
    pack_wt_kernel<<<dim3(6, 13, 1), 256, 0, stream>>>(
        patchW, nullptr, nullptr, 0, 0, 383, 784, 832, wt_patch, 0, 0, flag);
    if (full) {
        pack_wt_kernel<<<dim3(18, 6, 12), 256, 0, stream>>>(
            Wq, Wk, Wv, 0, (size_t)145152, 1134, 384, 384, wt_qkv, EQKV, 1, flag);
        pack_wt_kernel<<<dim3(6, 6, 12), 256, 0, stream>>>(
            Wo, nullptr, nullptr, 0, (size_t)147072, 383, 384, 384, wt_wo, EWO, 0, flag);
        pack_wt_kernel<<<dim3(24, 6, 12), 256, 0, stream>>>(
            W1, nullptr, nullptr, 0, (size_t)589440, 1535, 384, 384, wt_w1, EW1, 0, flag);
        pack_wt_kernel<<<dim3(6, 24, 12), 256, 0, stream>>>(
            W2, nullptr, nullptr, 0, (size_t)588288, 383, 1536, 1536, wt_w2, EW2, 0, flag);
    }

    // patch embed
    patchify_kernel<<<cdiv(CB * 224 * 224, 256), 256, 0, stream>>>(x, patches_bf, flag);
    padzero_kernel<<<cdiv(CROWS * (CKPP - CKP), 256), 256, 0, stream>>>(patches_bf);
    gemm_bt_kernel<64, 64><<<dim3(6, 128), 256, 0, stream>>>(
        patches_bf, CKPP, wt_patch, CKPP, bias_patch, big2, CDS, CKPP);
    add_time_rows_kernel<<<CROWS, 256, 0, stream>>>(big2, xln, CDS, 0, 0);
    lresnet_pe_kernel<<<CROWS, 256, 0, stream>>>(xln, pe, hbuf, flag);

    // LN1 of layer 0
    llayernorm_kernel<<<CROWS, 256, 0, stream>>>(
        hbuf, ln1g, 0, ln1b, 0, xln, xln_bf, flag);

    for (int l = 0; l < CL; l++) {
        const unsigned short *pqkv, *pwo, *pw1, *pw2;
        if (full) {
            pqkv = wt_qkv + (size_t)l * EQKV;
            pwo  = wt_wo  + (size_t)l * EWO;
            pw1  = wt_w1  + (size_t)l * EW1;
            pw2  = wt_w2  + (size_t)l * EW2;
        } else {
            pack_wt_kernel<<<dim3(18, 6, 1), 256, 0, stream>>>(
                Wq, Wk, Wv, (size_t)l * 145152, 0, 1134, 384, 384, l_qkv, 0, 1, flag);
            pack_wt_kernel<<<dim3(6, 6, 1), 256, 0, stream>>>(
                Wo, nullptr, nullptr, (size_t)l * 147072, 0, 383, 384, 384, l_wo, 0, 0, flag);
            pack_wt_kernel<<<dim3(24, 6, 1), 256, 0, stream>>>(
                W1, nullptr, nullptr, (size_t)l * 589440, 0, 1535, 384, 384, l_w1, 0, 0, flag);
            pack_wt_kernel<<<dim3(6, 24, 1), 256, 0, stream>>>(
                W2, nullptr, nullptr, (size_t)l * 588288, 0, 383, 1536, 1536, l_w2, 0, 0, flag);
            pqkv = l_qkv; pwo = l_wo; pw1 = l_w1; pw2 = l_w2;
        }
        // --- attention block ---
        gemm_bt_kernel<128, 128><<<dim3(9, 64), 256, 0, stream>>>(
            xln_bf, CD, pqkv, CD, bias_qkv + (size_t)l * 1152, big1, CQN3, CD);
        qkv_finish_kernel<<<2048, 256, 0, stream>>>(big1, qh, qlp, khp, vhp, vlp);
        attn_kernel<<<768, 256, 0, stream>>>(qh, qlp, khp, vhp, vlp, attcat_bf);
        gemm_bt_kernel<64, 64><<<dim3(6, 128), 256, 0, stream>>>(
            attcat_bf, CD, pwo, CD, bias_wo + (size_t)l * 384, big1, CDS, CD);
        addtime_lresnet_ln_kernel<<<CROWS, 256, 0, stream>>>(
            big1, xln, 27.5f, ln2g, (size_t)l * CDS, ln2b, (size_t)l * CDS,
            hbuf, xln, xln_bf, flag);
        // --- mlp block ---
        gemm_bt_kernel<128, 128><<<dim3(12, 64), 256, 0, stream>>>(
            xln_bf, CD, pw1, CD, bias_w1 + (size_t)l * 1536, big1, CMHS, CD);
        add_time_rows_kernel<<<CROWS, 256, 0, stream>>>(big1, hidden_bf, CMHS, 1, 1);
        gemm_bt_kernel<128, 128><<<dim3(3, 64), 256, 0, stream>>>(
            hidden_bf, CMH, pw2, CMH, bias_w2 + (size_t)l * 384, big1, CDS, CMH);
        if (l < CL - 1) {
            addtime_lresnet_ln_kernel<<<CROWS, 256, 0, stream>>>(
                big1, hbuf, 27.5f, ln1g, (size_t)(l + 1) * CDS, ln1b, (size_t)(l + 1) * CDS,
                hbuf, xln, xln_bf, flag);
        } else {
            addtime_lresnet_kernel<<<CROWS, 256, 0, stream>>>(big1, hbuf, 27.5f, hbuf);
        }
    }

    // head
    meanpool_part_kernel<<<dim3(CB, 8), 256, 0, stream>>>(hbuf, big1);
    meanpool_fin_kernel<<<CB, 256, 0, stream>>>(big1, emb);
    head_pre_kernel<<<250, 256, 0, stream>>>(mlra, mlrz, wt, beta, cha, flag);
    head_logits_kernel<<<250, 256, 0, stream>>>(emb, mlrz, wt, beta, cha, d_out, flag);
}

// Round 8
// 2674.886 us; speedup vs baseline: 1.0167x; 1.0167x over previous
//
#include <hip/hip_runtime.h>
#include <hip/hip_bf16.h>
#include <math.h>

typedef __hip_bfloat16 bf16;

// Problem constants
constexpr int CB   = 32;    // batch
constexpr int CN   = 256;   // tokens
constexpr int CD   = 384;   // model dim (incl. time)
constexpr int CDS  = 383;   // space dim
constexpr int CH   = 6;     // heads
constexpr int CHC  = 64;    // head channels (incl. time)
constexpr int CHCS = 63;    // head space channels
constexpr int CL   = 12;    // layers
constexpr int CMH  = 1536;  // mlp hidden (incl. time)
constexpr int CMHS = 1535;
constexpr int CROWS = CB * CN;        // 8192
constexpr int CKP  = 784;             // patch vector length (14*14*4)
constexpr int CKPP = 832;             // padded patch stride (mult of 64)
constexpr int CQN  = CH * CHCS;       // 378
constexpr int CQN3 = 3 * CQN;         // 1134 (fused qkv cols)

static inline int cdiv(int a, int b){ return (a + b - 1) / b; }

// MFMA frag types
typedef short bf8_t __attribute__((ext_vector_type(8)));
typedef float f4_t  __attribute__((ext_vector_type(4)));

// fp32 -> bf16 (RNE) raw
__device__ __forceinline__ unsigned short f2bf(float f) {
    union { float f; unsigned u; } x; x.f = f;
    unsigned r = x.u + 0x7FFFu + ((x.u >> 16) & 1u);
    return (unsigned short)(r >> 16);
}
__device__ __forceinline__ float bf2f(unsigned short h) {
    union { unsigned u; float f; } x; x.u = ((unsigned)h) << 16;
    return x.f;
}

// Dual-dtype input load: isb=1 -> bf16, isb=0 -> fp32. Wave-uniform isb.
__device__ __forceinline__ float ldin(const void* p, size_t i, int isb) {
    if (isb) return __bfloat162float(((const bf16*)p)[i]);
    return ((const float*)p)[i];
}

// ---------------------------------------------------------------------------
// Dtype detector (inputs fp32 expected; bf16 fallback).
// ---------------------------------------------------------------------------
__global__ __launch_bounds__(256)
void detect_kernel(const void* __restrict__ x, int* __restrict__ flag) {
    __shared__ int red[256];
    const unsigned short* u = (const unsigned short*)x;
    int cnt = 0;
    for (int i = threadIdx.x; i < 4096; i += 256) {
        unsigned short v = u[i];
        int e = (v >> 7) & 0xFF;
        cnt += (v == 0 || (e >= 96 && e <= 142)) ? 1 : 0;
    }
    red[threadIdx.x] = cnt;
    __syncthreads();
    for (int off = 128; off > 0; off >>= 1) {
        if (threadIdx.x < off) red[threadIdx.x] += red[threadIdx.x + off];
        __syncthreads();
    }
    if (threadIdx.x == 0) flag[0] = (red[0] >= 3482) ? 1 : 0;
}

// ---------------------------------------------------------------------------
// Weight pack: W[K,N] (fp32 or bf16; layer-strided) -> Wt[Npad][Kpad] bf16,
// transposed + zero-padded. fuse=1: fused-QKV col mapping from Wq/Wk/Wv.
// ---------------------------------------------------------------------------
__global__ __launch_bounds__(256)
void pack_wt_kernel(const void* __restrict__ Wa, const void* __restrict__ Wb,
                    const void* __restrict__ Wc, size_t srcBase, size_t srcStrideL,
                    int N, int K, int Kpad, unsigned short* __restrict__ dst,
                    size_t dstStrideL, int fuse, const int* __restrict__ flg) {
    int isb = flg[0];
    int n0 = blockIdx.x * 64, k0 = blockIdx.y * 64;
    size_t so = srcBase + srcStrideL * blockIdx.z;
    unsigned short* dl = dst + dstStrideL * blockIdx.z;
    __shared__ unsigned short t[64][65];
    int tid = threadIdx.x;
    #pragma unroll
    for (int it = 0; it < 16; ++it) {
        int flat = it * 256 + tid;
        int kk = flat >> 6, nn = flat & 63;
        int n = n0 + nn, k = k0 + kk;
        float v = 0.0f;
        if (n < N && k < K) {
            if (fuse) {
                int wh = n / 378, rem = n - wh * 378;
                int h = rem / 63, e = rem - h * 63;
                const void* s = (wh == 0) ? Wa : (wh == 1 ? Wb : Wc);
                v = ldin(s, so + ((size_t)h * 384 + k) * 63 + e, isb);
            } else {
                v = ldin(Wa, so + (size_t)k * N + n, isb);
            }
        }
        t[kk][nn] = f2bf(v);
    }
    __syncthreads();
    #pragma unroll
    for (int it = 0; it < 16; ++it) {
        int flat = it * 256 + tid;
        int nn = flat >> 6, kk = flat & 63;
        dl[(size_t)(n0 + nn) * Kpad + (k0 + kk)] = t[kk][nn];
    }
}

// Bias pack -> fp32 [L][Npad], zero-padded. fuse=1: fused qkv bias.
__global__ __launch_bounds__(256)
void pack_bias_kernel(const void* __restrict__ b0, const void* __restrict__ b1v,
                      const void* __restrict__ b2v, int N, int Npad, int fuse,
                      float* __restrict__ dst, const int* __restrict__ flg) {
    int isb = flg[0];
    int l = blockIdx.y;
    int n = blockIdx.x * 256 + threadIdx.x;
    if (n >= Npad) return;
    float v = 0.0f;
    if (n < N) {
        if (fuse) {
            int wh = n / 378, rem = n - wh * 378;
            const void* s = (wh == 0) ? b0 : (wh == 1 ? b1v : b2v);
            v = ldin(s, (size_t)l * 378 + rem, isb);
        } else {
            v = ldin(b0, (size_t)l * N + n, isb);
        }
    }
    dst[(size_t)l * Npad + n] = v;
}

// ---------------------------------------------------------------------------
// Patchify: x[B,3,224,224] -> patches[8192, CKPP] bf16 (stride-padded)
// ---------------------------------------------------------------------------
__global__ __launch_bounds__(256)
void patchify_kernel(const void* __restrict__ x, unsigned short* __restrict__ patches,
                     const int* __restrict__ flg) {
    int isb = flg[0];
    int idx = blockIdx.x * 256 + threadIdx.x;
    if (idx >= CB * 224 * 224) return;
    int col = idx % 224;
    int t   = idx / 224;
    int row = t % 224;
    int b   = t / 224;
    size_t base = ((size_t)b * 3) * 224 * 224 + (size_t)row * 224 + col;
    float r  = ldin(x, base, isb);
    float g  = ldin(x, base + 224 * 224, isb);
    float bl = ldin(x, base + 2 * 224 * 224, isb);
    float tt = sqrtf(1.0f + r * r + g * g + bl * bl);
    int gi = row / 14, pi = row % 14, gj = col / 14, pj = col % 14;
    int p = gi * 16 + gj;
    unsigned short* dp = patches + ((size_t)(b * CN + p)) * CKPP + (pi * 14 + pj) * 4;
    ushort4 w = make_ushort4(f2bf(tt), f2bf(r), f2bf(g), f2bf(bl));
    *(ushort4*)dp = w;
}

// zero the pad region [784, 832) of each patch row (bf16)
__global__ __launch_bounds__(256)
void padzero_kernel(unsigned short* __restrict__ patches) {
    int idx = blockIdx.x * 256 + threadIdx.x;
    if (idx >= CROWS * (CKPP - CKP)) return;
    int row = idx / (CKPP - CKP), off = idx % (CKPP - CKP);
    patches[(size_t)row * CKPP + CKP + off] = 0;
}

// ---------------------------------------------------------------------------
// MFMA GEMM v5: C[M,N] = A[M,lda] @ Bt[Npad,ldb]^T + bias.
// Software-pipelined 2-phase; XOR-swizzled LDS; MFMA order fixed.
// ---------------------------------------------------------------------------
template<int BM, int BN>
__global__ __launch_bounds__(256)
void gemm_bt_kernel(const unsigned short* __restrict__ A, int lda,
                    const unsigned short* __restrict__ Bt, int ldb,
                    const float* __restrict__ bias,
                    float* __restrict__ C, int N, int K) {
    constexpr int BK  = 64;
    constexpr int ACH = BM / 32;   // 16B staging chunks per thread (A)
    constexpr int BCH = BN / 32;
    constexpr int MFR = BM / 32;   // 16x16 m-frags per wave
    constexpr int NFR = BN / 32;
    __shared__ __align__(16) unsigned short As[BM * BK];
    __shared__ __align__(16) unsigned short Bs[BN * BK];
    const int tid = threadIdx.x;
    const int wave = tid >> 6, lane = tid & 63;
    const int wm = wave & 1, wn = wave >> 1;
    const int bm = blockIdx.y * BM, bn = blockIdx.x * BN;

    const unsigned short* aSrc[ACH]; unsigned short* aDst[ACH];
    #pragma unroll
    for (int it = 0; it < ACH; ++it) {
        int i = it * 256 + tid;
        int row = i >> 3, up = i & 7;
        aSrc[it] = A + (size_t)(bm + row) * lda + up * 8;
        aDst[it] = &As[row * BK + ((up ^ (row & 7)) * 8)];
    }
    const unsigned short* bSrc[BCH]; unsigned short* bDst[BCH];
    #pragma unroll
    for (int it = 0; it < BCH; ++it) {
        int i = it * 256 + tid;
        int row = i >> 3, up = i & 7;
        bSrc[it] = Bt + (size_t)(bn + row) * ldb + up * 8;
        bDst[it] = &Bs[row * BK + ((up ^ (row & 7)) * 8)];
    }

    f4_t acc[MFR][NFR] = {};
    bf8_t av[ACH], bv[BCH];
    #pragma unroll
    for (int it = 0; it < ACH; ++it) av[it] = *(const bf8_t*)(aSrc[it]);
    #pragma unroll
    for (int it = 0; it < BCH; ++it) bv[it] = *(const bf8_t*)(bSrc[it]);

    for (int k0 = 0; k0 < K; k0 += BK) {
        __syncthreads();   // previous tile's compute done -> LDS writable
        #pragma unroll
        for (int it = 0; it < ACH; ++it) *(bf8_t*)aDst[it] = av[it];
        #pragma unroll
        for (int it = 0; it < BCH; ++it) *(bf8_t*)bDst[it] = bv[it];
        __syncthreads();   // tile visible
        if (k0 + BK < K) {  // prefetch next tile; latency hides under MFMAs
            #pragma unroll
            for (int it = 0; it < ACH; ++it) av[it] = *(const bf8_t*)(aSrc[it] + k0 + BK);
            #pragma unroll
            for (int it = 0; it < BCH; ++it) bv[it] = *(const bf8_t*)(bSrc[it] + k0 + BK);
        }
        #pragma unroll
        for (int c = 0; c < 2; ++c) {
            bf8_t af[MFR], bfg[NFR];
            #pragma unroll
            for (int mi = 0; mi < MFR; ++mi) {
                int r = wm * (BM / 2) + mi * 16 + (lane & 15);
                int u = (c * 4 + (lane >> 4)) ^ (r & 7);
                af[mi] = *(const bf8_t*)&As[r * BK + u * 8];
            }
            #pragma unroll
            for (int ni = 0; ni < NFR; ++ni) {
                int cc = wn * (BN / 2) + ni * 16 + (lane & 15);
                int u = (c * 4 + (lane >> 4)) ^ (cc & 7);
                bfg[ni] = *(const bf8_t*)&Bs[cc * BK + u * 8];
            }
            #pragma unroll
            for (int mi = 0; mi < MFR; ++mi)
                #pragma unroll
                for (int ni = 0; ni < NFR; ++ni)
                    acc[mi][ni] = __builtin_amdgcn_mfma_f32_16x16x32_bf16(
                        af[mi], bfg[ni], acc[mi][ni], 0, 0, 0);
        }
    }

    const int colq = lane & 15, rowq = (lane >> 4) * 4;
    #pragma unroll
    for (int ni = 0; ni < NFR; ++ni) {
        int col = bn + wn * (BN / 2) + ni * 16 + colq;
        if (col >= N) continue;
        float bbv = bias[col];
        #pragma unroll
        for (int mi = 0; mi < MFR; ++mi) {
            int row = bm + wm * (BM / 2) + mi * 16 + rowq;
            #pragma unroll
            for (int r = 0; r < 4; ++r)
                C[(size_t)(row + r) * N + col] = acc[mi][ni][r] + bbv;
        }
    }
}

// ---------------------------------------------------------------------------
// add_time rows (+optional GELU). src [M,NS] fp32; dst [M,NS+1] fp32 (obf=0)
// or bf16 (obf=1). GELU tanh via overflow-safe __expf formulation.
// ---------------------------------------------------------------------------
__global__ __launch_bounds__(256)
void add_time_rows_kernel(const float* __restrict__ src, void* __restrict__ dst,
                          int NS, int do_gelu, int obf) {
    int row = blockIdx.x;
    int tid = threadIdx.x;
    __shared__ float buf[1536];
    __shared__ float red[256];
    const float* sr = src + (size_t)row * NS;
    float ss = 0.0f;
    for (int j = tid; j < NS; j += 256) {
        float vv = sr[j];
        if (do_gelu) {
            float x3 = vv * vv * vv;
            float u = 0.7978845608028654f * (vv + 0.044715f * x3);
            float e = __expf(-2.0f * fabsf(u));
            float th = copysignf((1.0f - e) / (1.0f + e), u);
            vv = 0.5f * vv * (1.0f + th);
        }
        buf[j] = vv;
        ss += vv * vv;
    }
    red[tid] = ss;
    __syncthreads();
    for (int off = 128; off > 0; off >>= 1) {
        if (tid < off) red[tid] += red[tid + off];
        __syncthreads();
    }
    float t = sqrtf(1.0f + red[0]);
    if (obf) {
        unsigned short* dr = (unsigned short*)dst + (size_t)row * (NS + 1);
        if (tid == 0) dr[0] = f2bf(t);
        for (int j = tid; j < NS; j += 256) dr[1 + j] = f2bf(buf[j]);
    } else {
        float* dr = (float*)dst + (size_t)row * (NS + 1);
        if (tid == 0) dr[0] = t;
        for (int j = tid; j < NS; j += 256) dr[1 + j] = buf[j];
    }
}

// ---------------------------------------------------------------------------
// Fused: out = lnormalize(base + scale * add_time(src)); src [M,383].
// (kept for the final layer where no LN follows)
// ---------------------------------------------------------------------------
__global__ __launch_bounds__(256)
void addtime_lresnet_kernel(const float* __restrict__ src,
                            const float* __restrict__ base, float scale,
                            float* __restrict__ out) {
    int row = blockIdx.x;
    int tid = threadIdx.x;
    const float* sr = src + (size_t)row * CDS;
    const float* br = base + (size_t)row * CD;
    __shared__ float red[256];
    float s0 = (tid > 0) ? sr[tid - 1] : 0.0f;
    float s1 = (tid < 128) ? sr[tid + 255] : 0.0f;
    red[tid] = s0 * s0 + s1 * s1;
    __syncthreads();
    for (int off = 128; off > 0; off >>= 1) {
        if (tid < off) red[tid] += red[tid + off];
        __syncthreads();
    }
    float t = sqrtf(1.0f + red[0]);
    __syncthreads();
    float y0 = (tid == 0) ? t : s0;
    float z0 = br[tid] + scale * y0;
    float z1 = (tid < 128) ? br[tid + 256] + scale * s1 : 0.0f;
    float c = (tid == 0) ? z0 * z0 : -z0 * z0;
    c -= z1 * z1;
    red[tid] = c;
    __syncthreads();
    for (int off = 128; off > 0; off >>= 1) {
        if (tid < off) red[tid] += red[tid + off];
        __syncthreads();
    }
    float rd = 1.0f / sqrtf(fmaxf(red[0], 1e-8f));
    float* orow = out + (size_t)row * CD;
    orow[tid] = z0 * rd;
    if (tid < 128) orow[256 + tid] = z1 * rd;
}

// ---------------------------------------------------------------------------
// Fused: h = lnormalize(base + scale*add_time(src));  hout <- h;
// then LorentzLayerNorm(h) -> lnout (fp32) + lnout_bf (bf16).
// ---------------------------------------------------------------------------
__global__ __launch_bounds__(256)
void addtime_lresnet_ln_kernel(const float* __restrict__ src,
                               const float* __restrict__ base, float scale,
                               const void* __restrict__ g, size_t goff,
                               const void* __restrict__ b, size_t boff,
                               float* __restrict__ hout,
                               float* __restrict__ lnout,
                               unsigned short* __restrict__ lnout_bf,
                               const int* __restrict__ flg) {
    int isb = flg[0];
    int row = blockIdx.x;
    int tid = threadIdx.x;
    const float* sr = src + (size_t)row * CDS;
    const float* br = base + (size_t)row * CD;
    __shared__ float red[256];
    __shared__ float red2[256];
    // --- add_time(src) ---
    float s0 = (tid > 0) ? sr[tid - 1] : 0.0f;
    float s1 = (tid < 128) ? sr[tid + 255] : 0.0f;
    red[tid] = s0 * s0 + s1 * s1;
    __syncthreads();
    for (int off = 128; off > 0; off >>= 1) {
        if (tid < off) red[tid] += red[tid + off];
        __syncthreads();
    }
    float t = sqrtf(1.0f + red[0]);
    __syncthreads();
    // --- lresnet ---
    float y0 = (tid == 0) ? t : s0;
    float z0 = br[tid] + scale * y0;
    float z1 = (tid < 128) ? br[256 + tid] + scale * s1 : 0.0f;
    float c = (tid == 0) ? z0 * z0 : -z0 * z0;
    c -= z1 * z1;
    red[tid] = c;
    __syncthreads();
    for (int off = 128; off > 0; off >>= 1) {
        if (tid < off) red[tid] += red[tid + off];
        __syncthreads();
    }
    float rd = 1.0f / sqrtf(fmaxf(red[0], 1e-8f));
    float h0 = z0 * rd;
    float h1 = z1 * rd;
    float* hr = hout + (size_t)row * CD;
    hr[tid] = h0;
    if (tid < 128) hr[256 + tid] = h1;
    __syncthreads();
    // --- layernorm over space ---
    float v0 = (tid > 0) ? h0 : 0.0f;
    float v1 = (tid < 128) ? h1 : 0.0f;
    red[tid]  = v0 + v1;
    red2[tid] = v0 * v0 + v1 * v1;
    __syncthreads();
    for (int off = 128; off > 0; off >>= 1) {
        if (tid < off) { red[tid] += red[tid + off]; red2[tid] += red2[tid + off]; }
        __syncthreads();
    }
    float mu  = red[0] * (1.0f / 383.0f);
    float var = red2[0] * (1.0f / 383.0f) - mu * mu;
    __syncthreads();
    float rstd = rsqrtf(var + 1e-5f);
    float w0 = 0.0f, w1 = 0.0f;
    if (tid > 0)
        w0 = (h0 - mu) * rstd * ldin(g, goff + tid - 1, isb) + ldin(b, boff + tid - 1, isb);
    if (tid < 128)
        w1 = (h1 - mu) * rstd * ldin(g, goff + 255 + tid, isb) + ldin(b, boff + 255 + tid, isb);
    red[tid] = w0 * w0 + w1 * w1;
    __syncthreads();
    for (int off = 128; off > 0; off >>= 1) {
        if (tid < off) red[tid] += red[tid + off];
        __syncthreads();
    }
    float t2 = sqrtf(1.0f + red[0]);
    float* orow = lnout + (size_t)row * CD;
    unsigned short* brow = lnout_bf + (size_t)row * CD;
    if (tid == 0) { orow[0] = t2; brow[0] = f2bf(t2); }
    else          { orow[tid] = w0; brow[tid] = f2bf(w0); }
    if (tid < 128) { orow[256 + tid] = w1; brow[256 + tid] = f2bf(w1); }
}

// ---------------------------------------------------------------------------
// Lorentz layernorm: x[M,384] -> out fp32 [M,384] + out_bf bf16 [M,384]
// ---------------------------------------------------------------------------
__global__ __launch_bounds__(256)
void llayernorm_kernel(const float* __restrict__ x, const void* __restrict__ g,
                       size_t goff, const void* __restrict__ b, size_t boff,
                       float* __restrict__ out, unsigned short* __restrict__ out_bf,
                       const int* __restrict__ flg) {
    int isb = flg[0];
    int row = blockIdx.x;
    int tid = threadIdx.x;
    const float* xr = x + (size_t)row * CD;
    __shared__ float red[256];
    __shared__ float red2[256];
    int j0 = tid, j1 = tid + 256;
    float v0 = xr[1 + j0];
    float v1 = (j1 < CDS) ? xr[1 + j1] : 0.0f;
    red[tid]  = v0 + v1;
    red2[tid] = v0 * v0 + v1 * v1;
    __syncthreads();
    for (int off = 128; off > 0; off >>= 1) {
        if (tid < off) { red[tid] += red[tid + off]; red2[tid] += red2[tid + off]; }
        __syncthreads();
    }
    float mu  = red[0] * (1.0f / 383.0f);
    float var = red2[0] * (1.0f / 383.0f) - mu * mu;
    __syncthreads();
    float rstd = rsqrtf(var + 1e-5f);
    float y0 = (v0 - mu) * rstd * ldin(g, goff + j0, isb) + ldin(b, boff + j0, isb);
    float y1 = 0.0f;
    if (j1 < CDS) y1 = (v1 - mu) * rstd * ldin(g, goff + j1, isb) + ldin(b, boff + j1, isb);
    red[tid] = y0 * y0 + y1 * y1;
    __syncthreads();
    for (int off = 128; off > 0; off >>= 1) {
        if (tid < off) red[tid] += red[tid + off];
        __syncthreads();
    }
    float t = sqrtf(1.0f + red[0]);
    float* orow = out + (size_t)row * CD;
    unsigned short* brow = out_bf + (size_t)row * CD;
    orow[1 + j0] = y0;  brow[1 + j0] = f2bf(y0);
    if (j1 < CDS) { orow[1 + j1] = y1; brow[1 + j1] = f2bf(y1); }
    if (tid == 0) { orow[0] = t; brow[0] = f2bf(t); }
}

// lresnet vs broadcast dual-dtype pe (scale = 1)
__global__ __launch_bounds__(256)
void lresnet_pe_kernel(const float* __restrict__ x, const void* __restrict__ pe,
                       float* __restrict__ out, const int* __restrict__ flg) {
    int isb = flg[0];
    int row = blockIdx.x;
    int tid = threadIdx.x;
    const float* xr = x + (size_t)row * CD;
    size_t pb = (size_t)(row & (CN - 1)) * CD;
    __shared__ float red[256];
    float z0 = xr[tid] + ldin(pe, pb + tid, isb);
    float z1 = 0.0f;
    float c = (tid == 0) ? z0 * z0 : -z0 * z0;
    if (tid < 128) { z1 = xr[256 + tid] + ldin(pe, pb + 256 + tid, isb); c -= z1 * z1; }
    red[tid] = c;
    __syncthreads();
    for (int off = 128; off > 0; off >>= 1) {
        if (tid < off) red[tid] += red[tid + off];
        __syncthreads();
    }
    float rd = 1.0f / sqrtf(fmaxf(red[0], 1e-8f));
    float* orow = out + (size_t)row * CD;
    orow[tid] = z0 * rd;
    if (tid < 128) orow[256 + tid] = z1 * rd;
}

// ---------------------------------------------------------------------------
// qkv finish v3: src[8192,1134] -> PRE-SPLIT bf16 planes with add_time:
//   qh/ql  [B*H,N,64]  (hi/lo split; time channel PRE-NEGATED -> attn copies)
//   kh     [B*H,N,64]  (hi only — QK compensation uses Q-lo only)
//   vh/vl  [B*H,N,64]  (hi/lo split)
// ---------------------------------------------------------------------------
__global__ __launch_bounds__(256)
void qkv_finish_kernel(const float* __restrict__ src,
                       unsigned short* __restrict__ qh, unsigned short* __restrict__ ql,
                       unsigned short* __restrict__ kh,
                       unsigned short* __restrict__ vh, unsigned short* __restrict__ vl) {
    int tid = threadIdx.x, wave = tid >> 6, lane = tid & 63;
    int row = blockIdx.x * 4 + wave;
    int b = row >> 8, n = row & 255;
    const float* srow = src + (size_t)row * CQN3;
    #pragma unroll
    for (int hs = 0; hs < 18; hs++) {
        int which = hs / 6, h = hs % 6;
        float y = (lane < CHCS) ? srow[hs * 63 + lane] : 0.0f;
        float ss = y * y;
        #pragma unroll
        for (int off = 32; off > 0; off >>= 1) ss += __shfl_xor(ss, off);
        float t = sqrtf(1.0f + ss);
        size_t base = (((size_t)(b * CH + h)) * CN + n) * CHC;
        if (which == 0) {
            if (lane < CHCS) {
                unsigned short hi = f2bf(y);
                qh[base + 1 + lane] = hi;
                ql[base + 1 + lane] = f2bf(y - bf2f(hi));
            }
            if (lane == 0) {
                float nt = -t;                 // Minkowski time sign pre-applied
                unsigned short hi = f2bf(nt);
                qh[base] = hi;
                ql[base] = f2bf(nt - bf2f(hi));
            }
        } else if (which == 1) {
            if (lane < CHCS) kh[base + 1 + lane] = f2bf(y);
            if (lane == 0)   kh[base] = f2bf(t);
        } else {
            if (lane < CHCS) {
                unsigned short hi = f2bf(y);
                vh[base + 1 + lane] = hi;
                vl[base + 1 + lane] = f2bf(y - bf2f(hi));
            }
            if (lane == 0) {
                unsigned short hi = f2bf(t);
                vh[base] = hi;
                vl[base] = f2bf(t - bf2f(hi));
            }
        }
    }
}

// ---------------------------------------------------------------------------
// Attention v7 (REVERTED from v8): pre-split bf16 planes + full barrier
// structure. Round-7 evidence: removing the inter-phase barriers serialized
// each wave's write->drain->read chain and cost +28us/dispatch; the barriers
// enforce phase-grouping (all waves store, then all MFMA) which the CU
// overlaps across waves. Keep all 11 PV-phase barriers.
// ---------------------------------------------------------------------------
__global__ __launch_bounds__(256)
void attn_kernel(const unsigned short* __restrict__ qh, const unsigned short* __restrict__ ql,
                 const unsigned short* __restrict__ kh,
                 const unsigned short* __restrict__ vh, const unsigned short* __restrict__ vl,
                 unsigned short* __restrict__ attcat) {
    __shared__ __align__(16) unsigned char smem[49152];
    unsigned short* Bk = (unsigned short*)smem;            // 32KB (QK phase)
    unsigned short* Pf = (unsigned short*)smem;            // 16KB (PV phase)
    unsigned short* Bv = (unsigned short*)(smem + 16384);  // 32KB (PV phase)
    int id = blockIdx.x;
    int nid = (id & 7) * 96 + (id >> 3);
    int bh = nid >> 2, qc = nid & 3;
    int h = bh % CH, b = bh / CH;
    int tid = threadIdx.x, wave = tid >> 6, lane = tid & 63;
    const unsigned short* qhb = qh + ((size_t)bh * CN + qc * 64) * CHC;
    const unsigned short* qlb = ql + ((size_t)bh * CN + qc * 64) * CHC;
    const unsigned short* khb = kh + (size_t)bh * CN * CHC;
    const unsigned short* vhb = vh + (size_t)bh * CN * CHC;
    const unsigned short* vlb = vl + (size_t)bh * CN * CHC;

    // ---- K staging: 16B u16 copies, swizzled b128 stores ----
    #pragma unroll
    for (int it = 0; it < 8; it++) {
        int flat = it * 256 + tid;
        int key = flat >> 3, c8 = flat & 7;
        bf8_t w = *(const bf8_t*)(khb + key * CHC + c8 * 8);
        int slab = (key >> 4) * 2 + (c8 >> 2);
        int lpw = ((key & 15) | ((c8 & 3) << 4)) ^ c8;
        *(bf8_t*)(Bk + (slab * 64 + lpw) * 8) = w;
    }

    // ---- Q fragments: direct u16 loads (hi + lo; time already negated) ----
    bf8_t ah[2], al[2];
    {
        int row = wave * 16 + (lane & 15);
        #pragma unroll
        for (int ks = 0; ks < 2; ks++) {
            int c4 = ks * 32 + (lane >> 4) * 8;
            ah[ks] = *(const bf8_t*)(qhb + row * CHC + c4);
            al[ks] = *(const bf8_t*)(qlb + row * CHC + c4);
        }
    }
    __syncthreads();

    // ---- QK^T (hi + lo compensation) ----
    int kx0 = lane ^ (lane >> 4);
    int kx1 = lane ^ (4 | (lane >> 4));
    f4_t s[16];
    #pragma unroll
    for (int nt = 0; nt < 16; nt++) s[nt] = (f4_t){0.0f, 0.0f, 0.0f, 0.0f};
    __builtin_amdgcn_s_setprio(1);
    #pragma unroll
    for (int nt = 0; nt < 16; nt++) {
        bf8_t b0 = *(const bf8_t*)(Bk + ((nt * 2 + 0) * 64 + kx0) * 8);
        bf8_t b1 = *(const bf8_t*)(Bk + ((nt * 2 + 1) * 64 + kx1) * 8);
        s[nt] = __builtin_amdgcn_mfma_f32_16x16x32_bf16(ah[0], b0, s[nt], 0, 0, 0);
        s[nt] = __builtin_amdgcn_mfma_f32_16x16x32_bf16(ah[1], b1, s[nt], 0, 0, 0);
        s[nt] = __builtin_amdgcn_mfma_f32_16x16x32_bf16(al[0], b0, s[nt], 0, 0, 0);
        s[nt] = __builtin_amdgcn_mfma_f32_16x16x32_bf16(al[1], b1, s[nt], 0, 0, 0);
    }
    __builtin_amdgcn_s_setprio(0);

    // ---- softmax (registers, wave-parallel) ----
    float mx[4] = {-1e30f, -1e30f, -1e30f, -1e30f};
    #pragma unroll
    for (int nt = 0; nt < 16; nt++)
        #pragma unroll
        for (int r = 0; r < 4; r++) mx[r] = fmaxf(mx[r], s[nt][r]);
    #pragma unroll
    for (int off = 1; off < 16; off <<= 1)
        #pragma unroll
        for (int r = 0; r < 4; r++) mx[r] = fmaxf(mx[r], __shfl_xor(mx[r], off));
    float sm[4] = {0.0f, 0.0f, 0.0f, 0.0f};
    #pragma unroll
    for (int nt = 0; nt < 16; nt++)
        #pragma unroll
        for (int r = 0; r < 4; r++) {
            float e = __expf(0.25f * (s[nt][r] - mx[r]));
            s[nt][r] = e; sm[r] += e;
        }
    #pragma unroll
    for (int off = 1; off < 16; off <<= 1)
        #pragma unroll
        for (int r = 0; r < 4; r++) sm[r] += __shfl_xor(sm[r], off);
    #pragma unroll
    for (int r = 0; r < 4; r++) sm[r] = 1.0f / sm[r];
    #pragma unroll
    for (int nt = 0; nt < 16; nt++)
        #pragma unroll
        for (int r = 0; r < 4; r++) s[nt][r] *= sm[r];

    __syncthreads();   // all QK reads of Bk complete (Pf/Bv alias it)

    int colq = lane & 15, quad = lane >> 4;
    // P half-write: slabs wave*4+ks2
    auto writePf = [&](int lo, int hh) {
        #pragma unroll
        for (int ntl = 0; ntl < 8; ntl++) {
            int nt = hh * 8 + ntl;
            int key = nt * 16 + colq;
            int ks2 = (key >> 5) & 3;
            #pragma unroll
            for (int r = 0; r < 4; r++) {
                int qrow = quad * 4 + r;
                int lp = (qrow & 15) | (((key >> 3) & 3) << 4);
                float p = s[nt][r];
                unsigned short hi = f2bf(p);
                unsigned short w = lo ? f2bf(p - bf2f(hi)) : hi;
                Pf[((wave * 4 + ks2) * 64 + lp) * 8 + (key & 7)] = w;
            }
        }
    };
    // V full-stage (256 keys): lane = dim, u16 copies, b128 LDS stores
    auto stageBv = [&](const unsigned short* plane) {
        #pragma unroll
        for (int i8 = 0; i8 < 8; i8++) {
            int oct = i8 * 4 + wave;
            bf8_t w;
            #pragma unroll
            for (int i = 0; i < 8; i++)
                w[i] = (short)plane[(size_t)(oct * 8 + i) * CHC + lane];
            int a16 = ((lane >> 4) * 8 + (oct >> 2)) * 64 + (oct & 3) * 16 + (lane & 15);
            *(bf8_t*)(Bv + a16 * 8) = w;
        }
    };
    f4_t o[4] = {};
    auto pvpass = [&](int hh) {
        __builtin_amdgcn_s_setprio(1);
        #pragma unroll
        for (int ks2 = 0; ks2 < 4; ks2++) {
            bf8_t pa = *(const bf8_t*)(Pf + ((wave * 4 + ks2) * 64 + lane) * 8);
            #pragma unroll
            for (int nt = 0; nt < 4; nt++) {
                bf8_t vv = *(const bf8_t*)(Bv + ((nt * 8 + hh * 4 + ks2) * 64 + lane) * 8);
                o[nt] = __builtin_amdgcn_mfma_f32_16x16x32_bf16(pa, vv, o[nt], 0, 0, 0);
            }
        }
        __builtin_amdgcn_s_setprio(0);
    };

    // V-hi resident: Ph*Vh (both halves), Pl*Vh; then V-lo: Ph*Vl.
    writePf(0, 0); stageBv(vhb);
    __syncthreads(); pvpass(0);
    __syncthreads(); writePf(0, 1);
    __syncthreads(); pvpass(1);
    __syncthreads(); writePf(1, 0);
    __syncthreads(); pvpass(0);
    __syncthreads(); writePf(1, 1);
    __syncthreads(); pvpass(1);
    __syncthreads(); writePf(0, 0); stageBv(vlb);
    __syncthreads(); pvpass(0);
    __syncthreads(); writePf(0, 1);
    __syncthreads(); pvpass(1);

    // ---- lnormalize + bf16 store ----
    {
        float nrm[4] = {0.0f, 0.0f, 0.0f, 0.0f};
        #pragma unroll
        for (int nt = 0; nt < 4; nt++) {
            float sgn = (nt == 0 && colq == 0) ? 1.0f : -1.0f;
            #pragma unroll
            for (int r = 0; r < 4; r++) nrm[r] += sgn * o[nt][r] * o[nt][r];
        }
        #pragma unroll
        for (int off = 1; off < 16; off <<= 1)
            #pragma unroll
            for (int r = 0; r < 4; r++) nrm[r] += __shfl_xor(nrm[r], off);
        #pragma unroll
        for (int r = 0; r < 4; r++) {
            float d = 1.0f / sqrtf(fmaxf(nrm[r], 1e-8f));
            int qg = qc * 64 + wave * 16 + quad * 4 + r;
            unsigned short* orow = attcat + ((size_t)b * CN + qg) * CD + h * CHC;
            #pragma unroll
            for (int nt = 0; nt < 4; nt++)
                orow[nt * 16 + colq] = f2bf(o[nt][r] * d);
        }
    }
}

// ---------------------------------------------------------------------------
// mean-pool v2: two-phase.
// ---------------------------------------------------------------------------
__global__ __launch_bounds__(256)
void meanpool_part_kernel(const float* __restrict__ hbuf, float* __restrict__ part) {
    int b = blockIdx.x, ch = blockIdx.y, tid = threadIdx.x;
    const float* hb = hbuf + ((size_t)b * CN + ch * 32) * CD;
    float s0 = 0.0f, s1 = 0.0f;
    for (int n = 0; n < 32; n++) {
        s0 += hb[(size_t)n * CD + tid];
        if (tid < 128) s1 += hb[(size_t)n * CD + 256 + tid];
    }
    float* pr = part + (size_t)(b * 8 + ch) * CD;
    pr[tid] = s0;
    if (tid < 128) pr[256 + tid] = s1;
}

__global__ __launch_bounds__(256)
void meanpool_fin_kernel(const float* __restrict__ part, float* __restrict__ emb) {
    int b = blockIdx.x, tid = threadIdx.x;
    float s0 = 0.0f, s1 = 0.0f;
    for (int c = 0; c < 8; c++) {
        const float* pr = part + (size_t)(b * 8 + c) * CD;
        s0 += pr[tid];
        if (tid < 128) s1 += pr[256 + tid];
    }
    s0 *= (1.0f / 256.0f);
    s1 *= (1.0f / 256.0f);
    __shared__ float red[256];
    float c2 = (tid == 0) ? s0 * s0 : -s0 * s0;
    if (tid < 128) c2 -= s1 * s1;
    red[tid] = c2;
    __syncthreads();
    for (int off = 128; off > 0; off >>= 1) {
        if (tid < off) red[tid] += red[tid + off];
        __syncthreads();
    }
    float rd = 1.0f / sqrtf(fmaxf(red[0], 1e-8f));
    emb[(size_t)b * CD + tid] = s0 * rd;
    if (tid < 128) emb[(size_t)b * CD + 256 + tid] = s1 * rd;
}

// ---------------------------------------------------------------------------
// MLR head precompute v2: wave-per-class, coalesced. grid (250), 256 thr.
// ---------------------------------------------------------------------------
__global__ __launch_bounds__(256)
void head_pre_kernel(const void* __restrict__ mlra, const void* __restrict__ mlrz,
                     float* __restrict__ wt, float* __restrict__ beta,
                     float* __restrict__ cha, const int* __restrict__ flg) {
    int isb = flg[0];
    int wave = threadIdx.x >> 6, lane = threadIdx.x & 63;
    int c = blockIdx.x * 4 + wave;
    float S = 0.0f;
    for (int j = lane; j < CDS; j += 64) {
        float zz = ldin(mlrz, (size_t)c * CDS + j, isb);
        S += zz * zz;
    }
    #pragma unroll
    for (int off = 32; off > 0; off >>= 1) S += __shfl_xor(S, off);
    if (lane == 0) {
        float a  = ldin(mlra, c, isb);
        float sh = sinhf(a), ch = coshf(a);
        float zn = sqrtf(S + 1e-8f);
        float w  = sh * zn;
        wt[c]  = w;
        cha[c] = ch;
        beta[c] = sqrtf(fmaxf(ch * ch * S - w * w, 1e-8f));
    }
}

// ---------------------------------------------------------------------------
// head logits v2: wave-per-class, lane-parallel over j, emb staged in LDS.
// ---------------------------------------------------------------------------
__global__ __launch_bounds__(256)
void head_logits_kernel(const float* __restrict__ emb, const void* __restrict__ mlrz,
                        const float* __restrict__ wt, const float* __restrict__ beta,
                        const float* __restrict__ cha, void* __restrict__ out,
                        const int* __restrict__ flg) {
    int isb = flg[0];
    int tid = threadIdx.x, wave = tid >> 6, lane = tid & 63;
    __shared__ float es[CB * CD];   // 48 KiB
    for (int i = tid; i < CB * CD; i += 256) es[i] = emb[i];
    __syncthreads();
    int c = blockIdx.x * 4 + wave;
    float zv[6];
    #pragma unroll
    for (int jj = 0; jj < 6; jj++) {
        int j = jj * 64 + lane;
        zv[jj] = (j < CDS) ? ldin(mlrz, (size_t)c * CDS + j, isb) : 0.0f;
    }
    float wtc = wt[c], chac = cha[c], bec = beta[c];
    for (int b = 0; b < CB; b++) {
        const float* eb = es + b * CD;
        float d = 0.0f;
        #pragma unroll
        for (int jj = 0; jj < 6; jj++) {
            int j = jj * 64 + lane;
            if (j < CDS) d += zv[jj] * eb[1 + j];
        }
        #pragma unroll
        for (int off = 32; off > 0; off >>= 1) d += __shfl_xor(d, off);
        if (lane == 0) {
            float alpha = -eb[0] * wtc + chac * d;
            float lg = bec * asinhf(alpha / bec);
            if (isb) ((bf16*)out)[(size_t)b * 1000 + c] = __float2bfloat16(lg);
            else     ((float*)out)[(size_t)b * 1000 + c] = lg;
        }
    }
}

// ---------------------------------------------------------------------------
// Orchestration. qkv planes (u16): qh|ql|kh|vh|vl each CROWS*CD elems,
// packed at big2 (2.5 FH floats total; xln_bf/attcat_bf at big2+3FH safe).
// ---------------------------------------------------------------------------
extern "C" void kernel_launch(void* const* d_in, const int* in_sizes, int n_in,
                              void* d_out, int out_size, void* d_ws, size_t ws_size,
                              hipStream_t stream) {
    const void* x      = d_in[0];
    const void* patchW = d_in[1];
    const void* patchB = d_in[2];
    const void* pe     = d_in[3];
    const void* ln1g   = d_in[4];
    const void* ln1b   = d_in[5];
    const void* ln2g   = d_in[6];
    const void* ln2b   = d_in[7];
    const void* Wq     = d_in[8];
    const void* bq     = d_in[9];
    const void* Wk     = d_in[10];
    const void* bk     = d_in[11];
    const void* Wv     = d_in[12];
    const void* bv     = d_in[13];
    const void* Wo     = d_in[14];
    const void* bo     = d_in[15];
    const void* W1     = d_in[16];
    const void* b1     = d_in[17];
    const void* W2     = d_in[18];
    const void* b2     = d_in[19];
    const void* mlra   = d_in[20];
    const void* mlrz   = d_in[21];

    float* ws = (float*)d_ws;
    const size_t FH = (size_t)CROWS * CD;
    float* hbuf   = ws;
    float* xln    = ws + FH;
    float* big1   = ws + 2 * FH;
    float* big2   = ws + 6 * FH;
    unsigned short* patches_bf = (unsigned short*)big1;
    unsigned short* hidden_bf  = (unsigned short*)big2;
    unsigned short* xln_bf     = (unsigned short*)(big2 + 3 * FH);
    unsigned short* attcat_bf  = (unsigned short*)(big2 + 3 * FH);
    // qkv bf16 planes (each FH u16 elems = FH/2 floats), total 2.5 FH floats
    unsigned short* qh  = (unsigned short*)big2;
    unsigned short* qlp = qh + FH;
    unsigned short* khp = qh + 2 * FH;
    unsigned short* vhp = qh + 3 * FH;
    unsigned short* vlp = qh + 4 * FH;
    float* emb    = ws + 10 * FH;
    float* wt     = emb + (size_t)CB * CD;
    float* beta   = wt + 1000;
    float* cha    = beta + 1000;
    int*   flag   = (int*)(cha + 1000);

    // packed biases (fp32)
    float* bias_patch = ws + 10 * FH + 16384;
    float* bias_qkv   = bias_patch + 384;
    float* bias_wo    = bias_qkv + (size_t)12 * 1152;
    float* bias_w1    = bias_wo  + (size_t)12 * 384;
    float* bias_w2    = bias_w1  + (size_t)12 * 1536;
    // packed weights (bf16)
    unsigned short* wt_patch = (unsigned short*)(bias_w2 + (size_t)12 * 384);
    unsigned short* wt_dyn   = wt_patch + (size_t)384 * 832;
    const size_t EQKV = (size_t)1152 * 384, EWO = (size_t)384 * 384,
                 EW1  = (size_t)1536 * 384, EW2 = (size_t)384 * 1536;
    unsigned short* wt_qkv = wt_dyn;
    unsigned short* wt_wo  = wt_qkv + 12 * EQKV;
    unsigned short* wt_w1  = wt_wo  + 12 * EWO;
    unsigned short* wt_w2  = wt_w1  + 12 * EW1;
    size_t need_full = (size_t)((char*)(wt_w2 + 12 * EW2) - (char*)d_ws);
    int full = (ws_size >= need_full) ? 1 : 0;
    // per-layer rotating buffers (aliased at wt_dyn)
    unsigned short* l_qkv = wt_dyn;
    unsigned short* l_wo  = l_qkv + EQKV;
    unsigned short* l_w1  = l_wo  + EWO;
    unsigned short* l_w2  = l_w1  + EW1;

    detect_kernel<<<1, 256, 0, stream>>>(x, flag);

    // pack biases
    pack_bias_kernel<<<dim3(2, 1),  256, 0, stream>>>(patchB, nullptr, nullptr, 383, 384, 0, bias_patch, flag);
    pack_bias_kernel<<<dim3(5, 12), 256, 0, stream>>>(bq, bk, bv, 1134, 1152, 1, bias_qkv, flag);
    pack_bias_kernel<<<dim3(2, 12), 256, 0, stream>>>(bo, nullptr, nullptr, 383, 384, 0, bias_wo, flag);
    pack_bias_kernel<<<dim3(6, 12), 256, 0, stream>>>(b1, nullptr, nullptr, 1535, 1536, 0, bias_w1, flag);
    pack_bias_kernel<<<dim3(2, 12), 256, 0, stream>>>(b2, nullptr, nullptr, 383, 384, 0, bias_w2, flag);

    // pack weights -> W^T bf16, zero-padded
    pack_wt_kernel<<<dim3(6, 13, 1), 256, 0, stream>>>(
        patchW, nullptr, nullptr, 0, 0, 383, 784, 832, wt_patch, 0, 0, flag);
    if (full) {
        pack_wt_kernel<<<dim3(18, 6, 12), 256, 0, stream>>>(
            Wq, Wk, Wv, 0, (size_t)145152, 1134, 384, 384, wt_qkv, EQKV, 1, flag);
        pack_wt_kernel<<<dim3(6, 6, 12), 256, 0, stream>>>(
            Wo, nullptr, nullptr, 0, (size_t)147072, 383, 384, 384, wt_wo, EWO, 0, flag);
        pack_wt_kernel<<<dim3(24, 6, 12), 256, 0, stream>>>(
            W1, nullptr, nullptr, 0, (size_t)589440, 1535, 384, 384, wt_w1, EW1, 0, flag);
        pack_wt_kernel<<<dim3(6, 24, 12), 256, 0, stream>>>(
            W2, nullptr, nullptr, 0, (size_t)588288, 383, 1536, 1536, wt_w2, EW2, 0, flag);
    }

    // patch embed
    patchify_kernel<<<cdiv(CB * 224 * 224, 256), 256, 0, stream>>>(x, patches_bf, flag);
    padzero_kernel<<<cdiv(CROWS * (CKPP - CKP), 256), 256, 0, stream>>>(patches_bf);
    gemm_bt_kernel<64, 64><<<dim3(6, 128), 256, 0, stream>>>(
        patches_bf, CKPP, wt_patch, CKPP, bias_patch, big2, CDS, CKPP);
    add_time_rows_kernel<<<CROWS, 256, 0, stream>>>(big2, xln, CDS, 0, 0);
    lresnet_pe_kernel<<<CROWS, 256, 0, stream>>>(xln, pe, hbuf, flag);

    // LN1 of layer 0
    llayernorm_kernel<<<CROWS, 256, 0, stream>>>(
        hbuf, ln1g, 0, ln1b, 0, xln, xln_bf, flag);

    for (int l = 0; l < CL; l++) {
        const unsigned short *pqkv, *pwo, *pw1, *pw2;
        if (full) {
            pqkv = wt_qkv + (size_t)l * EQKV;
            pwo  = wt_wo  + (size_t)l * EWO;
            pw1  = wt_w1  + (size_t)l * EW1;
            pw2  = wt_w2  + (size_t)l * EW2;
        } else {
            pack_wt_kernel<<<dim3(18, 6, 1), 256, 0, stream>>>(
                Wq, Wk, Wv, (size_t)l * 145152, 0, 1134, 384, 384, l_qkv, 0, 1, flag);
            pack_wt_kernel<<<dim3(6, 6, 1), 256, 0, stream>>>(
                Wo, nullptr, nullptr, (size_t)l * 147072, 0, 383, 384, 384, l_wo, 0, 0, flag);
            pack_wt_kernel<<<dim3(24, 6, 1), 256, 0, stream>>>(
                W1, nullptr, nullptr, (size_t)l * 589440, 0, 1535, 384, 384, l_w1, 0, 0, flag);
            pack_wt_kernel<<<dim3(6, 24, 1), 256, 0, stream>>>(
                W2, nullptr, nullptr, (size_t)l * 588288, 0, 383, 1536, 1536, l_w2, 0, 0, flag);
            pqkv = l_qkv; pwo = l_wo; pw1 = l_w1; pw2 = l_w2;
        }
        // --- attention block ---
        gemm_bt_kernel<128, 128><<<dim3(9, 64), 256, 0, stream>>>(
            xln_bf, CD, pqkv, CD, bias_qkv + (size_t)l * 1152, big1, CQN3, CD);
        qkv_finish_kernel<<<2048, 256, 0, stream>>>(big1, qh, qlp, khp, vhp, vlp);
        attn_kernel<<<768, 256, 0, stream>>>(qh, qlp, khp, vhp, vlp, attcat_bf);
        gemm_bt_kernel<64, 64><<<dim3(6, 128), 256, 0, stream>>>(
            attcat_bf, CD, pwo, CD, bias_wo + (size_t)l * 384, big1, CDS, CD);
        addtime_lresnet_ln_kernel<<<CROWS, 256, 0, stream>>>(
            big1, xln, 27.5f, ln2g, (size_t)l * CDS, ln2b, (size_t)l * CDS,
            hbuf, xln, xln_bf, flag);
        // --- mlp block ---
        gemm_bt_kernel<128, 128><<<dim3(12, 64), 256, 0, stream>>>(
            xln_bf, CD, pw1, CD, bias_w1 + (size_t)l * 1536, big1, CMHS, CD);
        add_time_rows_kernel<<<CROWS, 256, 0, stream>>>(big1, hidden_bf, CMHS, 1, 1);
        gemm_bt_kernel<128, 128><<<dim3(3, 64), 256, 0, stream>>>(
            hidden_bf, CMH, pw2, CMH, bias_w2 + (size_t)l * 384, big1, CDS, CMH);
        if (l < CL - 1) {
            addtime_lresnet_ln_kernel<<<CROWS, 256, 0, stream>>>(
                big1, hbuf, 27.5f, ln1g, (size_t)(l + 1) * CDS, ln1b, (size_t)(l + 1) * CDS,
                hbuf, xln, xln_bf, flag);
        } else {
            addtime_lresnet_kernel<<<CROWS, 256, 0, stream>>>(big1, hbuf, 27.5f, hbuf);
        }
    }

    // head
    meanpool_part_kernel<<<dim3(CB, 8), 256, 0, stream>>>(hbuf, big1);
    meanpool_fin_kernel<<<CB, 256, 0, stream>>>(big1, emb);
    head_pre_kernel<<<250, 256, 0, stream>>>(mlra, mlrz, wt, beta, cha, flag);
    head_logits_kernel<<<250, 256, 0, stream>>>(emb, mlrz, wt, beta, cha, d_out, flag);
}